// Round 1
// 208.205 us; speedup vs baseline: 1.0816x; 1.0816x over previous
//
#include <hip/hip_runtime.h>
#include <math.h>

// ---------------------------------------------------------------------------
// QuantumTransformerE2E on MI355X — R13.
// R12 (225 µs) + k_pre restructured as k_pre8: one block = 8 consecutive
// chunks of a batch row (grid 16384 -> 2048).
//  * weights / B-fragments / LN params loaded once per 8 chunks
//  * x staged in LDS with halo; conv reads are broadcast ds_read_b128
//  * chunk softmax computed once by 16 lanes into wl[16] (was 128x redundant)
//  * pp/ep projection batched over the 8 chunks: weight loads /8
//    (L2 traffic 1 GB -> 0.13 GB), pp+ep unified into one exec path
// k_circ_cs / k_circ / k_post / k_pool_cf and tier3 fallback verbatim R12.
// ---------------------------------------------------------------------------

constexpr int kNQ    = 6;
constexpr int kDM    = 128;
constexpr int kCH    = 4;
constexpr int kSEQ   = 2048;
constexpr int kCHUNK = 16;
constexpr int kBATCH = 128;
constexpr int kNCH   = kSEQ / kCHUNK;  // 128
constexpr int kNP    = 120;
constexpr float kPI  = 3.14159265358979323846f;

typedef __attribute__((ext_vector_type(8))) short bf16x8;
typedef __attribute__((ext_vector_type(4))) float f32x4;

__device__ __forceinline__ float fast_tanh(float x) {
  float e = __expf(-2.f * fabsf(x));
  float r = (1.f - e) * __builtin_amdgcn_rcpf(1.f + e);
  return copysignf(r, x);
}
__device__ __forceinline__ float fast_silu(float x) {
  return x * __builtin_amdgcn_rcpf(1.f + __expf(-x));
}

// quad_perm DPP helpers (VALU pipe).
template <int XM>
__device__ __forceinline__ float qp(float v) {
  constexpr int ctrl = (XM == 1) ? 0xB1 : 0x4E;
  return __int_as_float(
      __builtin_amdgcn_update_dpp(0, __float_as_int(v), ctrl, 0xF, 0xF, true));
}

// ---- register-resident 6-qubit gates (verified R8/R10) ---------------------

template <int RB>
__device__ __forceinline__ void rx_reg(float c, float s, float* sr, float* si) {
#pragma unroll
  for (int r0 = 0; r0 < 16; ++r0) {
    if (r0 & RB) continue;
    int r1 = r0 | RB;
    float ar = sr[r0], ai = si[r0], br = sr[r1], bi = si[r1];
    sr[r0] = fmaf(c, ar,  s * bi);  si[r0] = fmaf(c, ai, -s * br);
    sr[r1] = fmaf(c, br,  s * ai);  si[r1] = fmaf(c, bi, -s * ar);
  }
}

template <int RB>
__device__ __forceinline__ void ry_reg(float c, float s, float* sr, float* si) {
#pragma unroll
  for (int r0 = 0; r0 < 16; ++r0) {
    if (r0 & RB) continue;
    int r1 = r0 | RB;
    float ar = sr[r0], ai = si[r0], br = sr[r1], bi = si[r1];
    sr[r0] = fmaf(c, ar, -s * br);  si[r0] = fmaf(c, ai, -s * bi);
    sr[r1] = fmaf(s, ar,  c * br);  si[r1] = fmaf(s, ai,  c * bi);
  }
}

template <int RB>
__device__ __forceinline__ void rz_reg(float c, float s, float* sr, float* si) {
#pragma unroll
  for (int r = 0; r < 16; ++r) {
    float sp = (r & RB) ? s : -s;
    float ar = sr[r], ai = si[r];
    sr[r] = fmaf(c, ar, -sp * ai);
    si[r] = fmaf(c, ai,  sp * ar);
  }
}

template <int XM>
__device__ __forceinline__ void rx_lane(float c, float s, float* sr, float* si) {
#pragma unroll
  for (int r = 0; r < 16; ++r) {
    float pr = qp<XM>(sr[r]), pi = qp<XM>(si[r]);
    sr[r] = fmaf(c, sr[r],  s * pi);
    si[r] = fmaf(c, si[r], -s * pr);
  }
}

template <int XM>
__device__ __forceinline__ void ry_lane(float c, float sg, float* sr, float* si) {
#pragma unroll
  for (int r = 0; r < 16; ++r) {
    float pr = qp<XM>(sr[r]), pi = qp<XM>(si[r]);
    sr[r] = fmaf(c, sr[r], sg * pr);
    si[r] = fmaf(c, si[r], sg * pi);
  }
}

__device__ __forceinline__ void rz_lane(float c, float sp, float* sr, float* si) {
#pragma unroll
  for (int r = 0; r < 16; ++r) {
    float ar = sr[r], ai = si[r];
    sr[r] = fmaf(c, ar, -sp * ai);
    si[r] = fmaf(c, ai,  sp * ar);
  }
}

template <int RB, int CB>
__device__ __forceinline__ void crx_reg_reg(float c, float s, float* sr, float* si) {
#pragma unroll
  for (int r0 = 0; r0 < 16; ++r0) {
    if ((r0 & RB) || !(r0 & CB)) continue;
    int r1 = r0 | RB;
    float ar = sr[r0], ai = si[r0], br = sr[r1], bi = si[r1];
    sr[r0] = fmaf(c, ar,  s * bi);  si[r0] = fmaf(c, ai, -s * br);
    sr[r1] = fmaf(c, br,  s * ai);  si[r1] = fmaf(c, bi, -s * ar);
  }
}

template <int XM, int CB>
__device__ __forceinline__ void crx_reg_lane(float c, float s, float* sr, float* si) {
#pragma unroll
  for (int r = 0; r < 16; ++r) {
    if (!(r & CB)) continue;
    float pr = qp<XM>(sr[r]), pi = qp<XM>(si[r]);
    sr[r] = fmaf(c, sr[r],  s * pi);
    si[r] = fmaf(c, si[r], -s * pr);
  }
}

template <int RB>
__device__ __forceinline__ void meas_reg(const float* sr, const float* si,
                                         float& tr, float& ti, float& zz) {
  tr = 0.f; ti = 0.f; zz = 0.f;
#pragma unroll
  for (int r0 = 0; r0 < 16; ++r0) {
    float n = fmaf(sr[r0], sr[r0], si[r0] * si[r0]);
    zz += (r0 & RB) ? -n : n;
    if (r0 & RB) continue;
    int r1 = r0 | RB;
    tr = fmaf(sr[r0], sr[r1], fmaf(si[r0], si[r1], tr));
    ti = fmaf(sr[r0], si[r1], fmaf(-si[r0], sr[r1], ti));
  }
  tr += qp<1>(tr); tr += qp<2>(tr);
  ti += qp<1>(ti); ti += qp<2>(ti);
  zz += qp<1>(zz); zz += qp<2>(zz);
}

// ---------------------------------------------------------------------------
// k_pre8: conv + LN1 + MFMA chunk attention + batched projections.
// One block = 8 consecutive chunks of one batch row. 128 threads.
// emit_cs=1: (cos,sin) of half-angles, stride 256 floats/chunk.
// emit_cs=0: half-angles, stride 126 floats/chunk (tier2).

__global__ __launch_bounds__(128) void k_pre8(
    const float* __restrict__ x,
    const float* __restrict__ conv_w, const float* __restrict__ conv_b,
    const float* __restrict__ ln1_g,  const float* __restrict__ ln1_b,
    const float* __restrict__ ca1_w,  const float* __restrict__ ca1_b,
    const float* __restrict__ ca2_w,  const float* __restrict__ ca2_b,
    const float* __restrict__ pp_w,   const float* __restrict__ pp_b,
    const float* __restrict__ ep_w,   const float* __restrict__ ep_b,
    float* __restrict__ outb, int emit_cs)
{
  constexpr int NC = 8;  // chunks per block

  __shared__ __align__(16) float xs[kCH][NC * kCHUNK + 4];  // halo'd x segment
  __shared__ __align__(16) float hbuf[kCHUNK][132];
  __shared__ __align__(16) float spart[2][16];
  __shared__ __align__(16) float wl[kCHUNK];
  __shared__ __align__(16) float sums[NC][kDM];
  __shared__ float mrow[kCHUNK], irow[kCHUNK];

  const int tid    = threadIdx.x;
  const int chunk0 = blockIdx.x * NC;
  const int b      = chunk0 >> 7;
  const int tloc   = (chunk0 & 127) * kCHUNK;  // segment start within row
  const int d      = tid;
  const int lane   = tid & 63;
  const int wv     = tid >> 6;
  const int col    = (lane & 15) + 16 * wv;
  const int qd     = lane >> 4;

  // ---- per-block weight setup (once per 8 chunks) ----
  float w12[12];
  {
    const float4* cw = (const float4*)(conv_w + d * 12);
    float4 a0 = cw[0], a1 = cw[1], a2 = cw[2];
    w12[0]=a0.x; w12[1]=a0.y; w12[2]=a0.z; w12[3]=a0.w;
    w12[4]=a1.x; w12[5]=a1.y; w12[6]=a1.z; w12[7]=a1.w;
    w12[8]=a2.x; w12[9]=a2.y; w12[10]=a2.z; w12[11]=a2.w;
  }
  float cb = conv_b[d];
  float g1 = ln1_g[d], b1 = ln1_b[d];
  float cb1 = ca1_b[col], cw2 = ca2_w[col], cb2 = ca2_b[0];

  bf16x8 bhi[4], blo[4];
#pragma unroll
  for (int ks = 0; ks < 4; ++ks)
#pragma unroll
    for (int jj = 0; jj < 8; ++jj) {
      float bvf = ca1_w[(ks * 32 + qd * 8 + jj) * 32 + col];
      unsigned bb = __float_as_uint(bvf);
      bhi[ks][jj] = (short)(bb >> 16);
      float lf = bvf - __uint_as_float(bb & 0xffff0000u);
      blo[ks][jj] = (short)(__float_as_uint(lf) >> 16);
    }

  // ---- stage x segment with halo: positions [tloc-1, tloc+128] ----
#pragma unroll
  for (int ch = 0; ch < kCH; ++ch) {
#pragma unroll
    for (int base = 0; base < 2; ++base) {
      int pos = base * 128 + tid;
      if (pos < NC * kCHUNK + 2) {
        int s = tloc - 1 + pos;
        float v = 0.f;
        if (s >= 0 && s < kSEQ) v = x[((size_t)b * kCH + ch) * kSEQ + s];
        xs[ch][pos] = v;
      }
    }
  }
  __syncthreads();

  for (int c = 0; c < NC; ++c) {
    // ---- conv from LDS (broadcast reads) ----
    float h[kCHUNK];
#pragma unroll
    for (int t = 0; t < kCHUNK; ++t) h[t] = cb;
#pragma unroll
    for (int ch = 0; ch < kCH; ++ch) {
      const float4* xp = (const float4*)&xs[ch][c * kCHUNK];
      float4 v0 = xp[0], v1 = xp[1], v2 = xp[2], v3 = xp[3], v4 = xp[4];
      float xr[18];
      xr[0]=v0.x; xr[1]=v0.y; xr[2]=v0.z; xr[3]=v0.w;
      xr[4]=v1.x; xr[5]=v1.y; xr[6]=v1.z; xr[7]=v1.w;
      xr[8]=v2.x; xr[9]=v2.y; xr[10]=v2.z; xr[11]=v2.w;
      xr[12]=v3.x; xr[13]=v3.y; xr[14]=v3.z; xr[15]=v3.w;
      xr[16]=v4.x; xr[17]=v4.y;
      float c0 = w12[ch*3+0], c1 = w12[ch*3+1], c2 = w12[ch*3+2];
#pragma unroll
      for (int t = 0; t < kCHUNK; ++t)
        h[t] = fmaf(xr[t], c0, fmaf(xr[t+1], c1, fmaf(xr[t+2], c2, h[t])));
    }
#pragma unroll
    for (int t = 0; t < kCHUNK; ++t) hbuf[t][d] = h[t];
    __syncthreads();

    // ---- LN stats (verbatim) ----
    {
      int row = tid >> 3, k = tid & 7;
      const float4* rp = (const float4*)&hbuf[row][k * 16];
      float s1 = 0.f, s2 = 0.f;
#pragma unroll
      for (int q = 0; q < 4; ++q) {
        float4 v = rp[q];
        s1 += v.x + v.y + v.z + v.w;
        s2 = fmaf(v.x,v.x,s2); s2 = fmaf(v.y,v.y,s2);
        s2 = fmaf(v.z,v.z,s2); s2 = fmaf(v.w,v.w,s2);
      }
#pragma unroll
      for (int o = 1; o < 8; o <<= 1) {
        s1 += __shfl_xor(s1, o, 64);
        s2 += __shfl_xor(s2, o, 64);
      }
      if (k == 0) {
        float m = s1 * (1.f / kDM);
        mrow[row] = m;
        irow[row] = rsqrtf(s2 * (1.f / kDM) - m * m + 1e-5f);
      }
    }
    __syncthreads();

    // ---- LN apply + bf16 hi/lo pack into hbuf (verbatim) ----
#pragma unroll
    for (int t = 0; t < kCHUNK; ++t) {
      h[t] = fmaf((h[t] - mrow[t]) * irow[t], g1, b1);
      unsigned hb = __float_as_uint(h[t]);
      float lof = h[t] - __uint_as_float(hb & 0xffff0000u);
      unsigned pk = (hb >> 16) | (__float_as_uint(lof) & 0xffff0000u);
      ((unsigned*)&hbuf[t][0])[d] = pk;
    }
    __syncthreads();

    // ---- MFMA chunk-attention scores (verbatim) ----
    f32x4 acc = {0.f, 0.f, 0.f, 0.f};
    {
      const unsigned* hrow = (const unsigned*)&hbuf[lane & 15][0];
#pragma unroll
      for (int ks = 0; ks < 4; ++ks) {
        const uint4* ap = (const uint4*)(hrow + ks * 32 + qd * 8);
        uint4 w0 = ap[0], w1 = ap[1];
        bf16x8 ahi, alo;
        ahi[0] = (short)(w0.x & 0xffff); ahi[1] = (short)(w0.y & 0xffff);
        ahi[2] = (short)(w0.z & 0xffff); ahi[3] = (short)(w0.w & 0xffff);
        ahi[4] = (short)(w1.x & 0xffff); ahi[5] = (short)(w1.y & 0xffff);
        ahi[6] = (short)(w1.z & 0xffff); ahi[7] = (short)(w1.w & 0xffff);
        alo[0] = (short)(w0.x >> 16); alo[1] = (short)(w0.y >> 16);
        alo[2] = (short)(w0.z >> 16); alo[3] = (short)(w0.w >> 16);
        alo[4] = (short)(w1.x >> 16); alo[5] = (short)(w1.y >> 16);
        alo[6] = (short)(w1.z >> 16); alo[7] = (short)(w1.w >> 16);
        acc = __builtin_amdgcn_mfma_f32_16x16x32_bf16(ahi, bhi[ks], acc, 0, 0, 0);
        acc = __builtin_amdgcn_mfma_f32_16x16x32_bf16(ahi, blo[ks], acc, 0, 0, 0);
        acc = __builtin_amdgcn_mfma_f32_16x16x32_bf16(alo, bhi[ks], acc, 0, 0, 0);
      }
    }

    // ---- tanh + ca2 + reduce over 16 cols -> spart (verbatim) ----
    {
      float ev[4];
#pragma unroll
      for (int r = 0; r < 4; ++r)
        ev[r] = fast_tanh(acc[r] + cb1) * cw2;
#pragma unroll
      for (int o = 1; o < 16; o <<= 1)
#pragma unroll
        for (int r = 0; r < 4; ++r) ev[r] += __shfl_xor(ev[r], o, 64);
      if ((lane & 15) == 0)
        *(float4*)&spart[wv][qd * 4] = make_float4(ev[0], ev[1], ev[2], ev[3]);
    }
    __syncthreads();

    // ---- softmax weights computed once by 16 lanes -> wl ----
    if (tid < 16) {
      float scl = spart[0][tid] + spart[1][tid] + cb2;
      float mx = scl;
#pragma unroll
      for (int o = 1; o < 16; o <<= 1) mx = fmaxf(mx, __shfl_xor(mx, o, 64));
      float e = __expf(scl - mx);
      float se = e;
#pragma unroll
      for (int o = 1; o < 16; o <<= 1) se += __shfl_xor(se, o, 64);
      wl[tid] = e * (1.f / se);
    }
    __syncthreads();

    // ---- weighted pool -> sums[c][d] ----
    {
      const float4* w4 = (const float4*)wl;
      float4 wa = w4[0], wb = w4[1], wc = w4[2], wd = w4[3];
      float acc2 = 0.f;
      acc2 = fmaf(wa.x, h[0],  acc2); acc2 = fmaf(wa.y, h[1],  acc2);
      acc2 = fmaf(wa.z, h[2],  acc2); acc2 = fmaf(wa.w, h[3],  acc2);
      acc2 = fmaf(wb.x, h[4],  acc2); acc2 = fmaf(wb.y, h[5],  acc2);
      acc2 = fmaf(wb.z, h[6],  acc2); acc2 = fmaf(wb.w, h[7],  acc2);
      acc2 = fmaf(wc.x, h[8],  acc2); acc2 = fmaf(wc.y, h[9],  acc2);
      acc2 = fmaf(wc.z, h[10], acc2); acc2 = fmaf(wc.w, h[11], acc2);
      acc2 = fmaf(wd.x, h[12], acc2); acc2 = fmaf(wd.y, h[13], acc2);
      acc2 = fmaf(wd.z, h[14], acc2); acc2 = fmaf(wd.w, h[15], acc2);
      sums[c][d] = acc2;
    }
    // next chunk's hbuf/mrow writes are barrier-protected by its own syncs
  }
  __syncthreads();

  // ---- batched pp/ep projection: one weight load feeds 8 chunks ----
  if (tid < kNP + kNQ) {
    const bool isep = (tid >= kNP);
    const int  jj   = tid - kNP;
    const float* wp = isep ? (ep_w + jj) : (pp_w + tid);
    const int  ws   = isep ? kNQ : kNP;
    const int  ws2  = ws * 2, ws3 = ws * 3, ws4 = ws * 4;
    float bias = isep ? ep_b[jj] : pp_b[tid];
    float accp[NC];
#pragma unroll
    for (int c = 0; c < NC; ++c) accp[c] = bias;
#pragma unroll 4
    for (int q4 = 0; q4 < 32; ++q4) {
      float w0 = wp[0], w1 = wp[ws], w2 = wp[ws2], w3 = wp[ws3];
      wp += ws4;
#pragma unroll
      for (int c = 0; c < NC; ++c) {
        float4 s = *(const float4*)&sums[c][q4 * 4];
        accp[c] = fmaf(s.x, w0, fmaf(s.y, w1, fmaf(s.z, w2, fmaf(s.w, w3, accp[c]))));
      }
    }
    const int slot = isep ? jj : (6 + tid);
#pragma unroll
    for (int c = 0; c < NC; ++c) {
      int chunkg = chunk0 + c;
      float ha = isep ? (0.5f * fast_tanh(accp[c]) * kPI) : (0.5f * accp[c]);
      if (emit_cs) {
        ((float2*)(outb + (size_t)chunkg * 256))[slot] =
            make_float2(__cosf(ha), __sinf(ha));
      } else {
        outb[(size_t)chunkg * 126 + slot] = ha;
      }
    }
  }
}

// ---------------------------------------------------------------------------
// k_circ_cs: tier1 — LDS-staged (cos,sin); zero transcendentals, bulk global
// load (16 coalesced float4/lane) replaces 126 exposed global loads.

constexpr int kCsStride = 260;  // floats; b128-aligned (1040 B), <=2-way bank alias

__global__ __launch_bounds__(64) void k_circ_cs(const float* __restrict__ csA,
                                                float* __restrict__ qv_g)
{
  __shared__ __align__(16) float lds[16 * kCsStride];  // 16.6 KB

  const int lane  = threadIdx.x;
  const int c     = lane >> 2;
  const int l     = lane & 3;
  const int chunk = blockIdx.x * 16 + c;
  const int b0 = (l >> 1) & 1;
  const int b1 = l & 1;

  // ---- stage: iteration i copies chunk i's 256 floats ----
  {
    const float4* src = (const float4*)(csA + (size_t)blockIdx.x * 16 * 256);
#pragma unroll
    for (int i = 0; i < 16; ++i) {
      float4 v = src[i * 64 + lane];
      *(float4*)&lds[i * kCsStride + lane * 4] = v;
    }
  }
  __syncthreads();

  const float2* cp = (const float2*)&lds[c * kCsStride];

  float sr[16], si[16];
#pragma unroll
  for (int r = 0; r < 16; ++r) { sr[r] = 0.f; si[r] = 0.f; }
  sr[0] = (l == 0) ? 1.f : 0.f;

  {
    float2 q0 = cp[0], q1 = cp[1], q2 = cp[2], q3 = cp[3], q4 = cp[4], q5 = cp[5];
    ry_lane<2>(q0.x, b0 ? q0.y : -q0.y, sr, si);
    ry_lane<1>(q1.x, b1 ? q1.y : -q1.y, sr, si);
    ry_reg<8>(q2.x, q2.y, sr, si);
    ry_reg<4>(q3.x, q3.y, sr, si);
    ry_reg<2>(q4.x, q4.y, sr, si);
    ry_reg<1>(q5.x, q5.y, sr, si);
  }

  for (int a = 0; a < 4; ++a) {
    const float2* pb = cp + 6 + a * 30;
    float2 t;
    t = pb[0];  rx_lane<2>(t.x, t.y, sr, si);
    t = pb[1];  ry_lane<2>(t.x, b0 ? t.y : -t.y, sr, si);
    t = pb[2];  rz_lane   (t.x, b0 ? t.y : -t.y, sr, si);
    t = pb[3];  rx_lane<1>(t.x, t.y, sr, si);
    t = pb[4];  ry_lane<1>(t.x, b1 ? t.y : -t.y, sr, si);
    t = pb[5];  rz_lane   (t.x, b1 ? t.y : -t.y, sr, si);
    t = pb[6];  rx_reg<8>(t.x, t.y, sr, si);
    t = pb[7];  ry_reg<8>(t.x, t.y, sr, si);
    t = pb[8];  rz_reg<8>(t.x, t.y, sr, si);
    t = pb[9];  rx_reg<4>(t.x, t.y, sr, si);
    t = pb[10]; ry_reg<4>(t.x, t.y, sr, si);
    t = pb[11]; rz_reg<4>(t.x, t.y, sr, si);
    t = pb[12]; rx_reg<2>(t.x, t.y, sr, si);
    t = pb[13]; ry_reg<2>(t.x, t.y, sr, si);
    t = pb[14]; rz_reg<2>(t.x, t.y, sr, si);
    t = pb[15]; rx_reg<1>(t.x, t.y, sr, si);
    t = pb[16]; ry_reg<1>(t.x, t.y, sr, si);
    t = pb[17]; rz_reg<1>(t.x, t.y, sr, si);
    t = pb[18]; { float c2 = b0 ? t.x : 1.f, s2 = b0 ? t.y : 0.f; rx_lane<1>(c2, s2, sr, si); }
    t = pb[19]; { float c2 = b1 ? t.x : 1.f, s2 = b1 ? t.y : 0.f; rx_reg<8>(c2, s2, sr, si); }
    t = pb[20]; crx_reg_reg<4, 8>(t.x, t.y, sr, si);
    t = pb[21]; crx_reg_reg<2, 4>(t.x, t.y, sr, si);
    t = pb[22]; crx_reg_reg<1, 2>(t.x, t.y, sr, si);
    t = pb[23]; crx_reg_lane<2, 1>(t.x, t.y, sr, si);
    t = pb[24]; crx_reg_reg<2, 1>(t.x, t.y, sr, si);
    t = pb[25]; crx_reg_reg<4, 2>(t.x, t.y, sr, si);
    t = pb[26]; crx_reg_reg<8, 4>(t.x, t.y, sr, si);
    t = pb[27]; crx_reg_lane<1, 8>(t.x, t.y, sr, si);
    t = pb[28]; { float c2 = b1 ? t.x : 1.f, s2 = b1 ? t.y : 0.f; rx_lane<2>(c2, s2, sr, si); }
    t = pb[29]; { float c2 = b0 ? t.x : 1.f, s2 = b0 ? t.y : 0.f; rx_reg<1>(c2, s2, sr, si); }
  }

  float res[18];
  {
    float tr = 0.f, ti = 0.f, zz = 0.f;
#pragma unroll
    for (int r = 0; r < 16; ++r) {
      float pr = qp<2>(sr[r]), pi = qp<2>(si[r]);
      tr = fmaf(sr[r], pr, fmaf(si[r], pi, tr));
      ti = fmaf(sr[r], pi, fmaf(-si[r], pr, ti));
      zz = fmaf(sr[r], sr[r], fmaf(si[r], si[r], zz));
    }
    tr = b0 ? 0.f : tr;  ti = b0 ? 0.f : ti;  zz = b0 ? -zz : zz;
    tr += qp<1>(tr); tr += qp<2>(tr);
    ti += qp<1>(ti); ti += qp<2>(ti);
    zz += qp<1>(zz); zz += qp<2>(zz);
    res[0] = 2.f * tr; res[6] = 2.f * ti; res[12] = zz;
  }
  {
    float tr = 0.f, ti = 0.f, zz = 0.f;
#pragma unroll
    for (int r = 0; r < 16; ++r) {
      float pr = qp<1>(sr[r]), pi = qp<1>(si[r]);
      tr = fmaf(sr[r], pr, fmaf(si[r], pi, tr));
      ti = fmaf(sr[r], pi, fmaf(-si[r], pr, ti));
      zz = fmaf(sr[r], sr[r], fmaf(si[r], si[r], zz));
    }
    tr = b1 ? 0.f : tr;  ti = b1 ? 0.f : ti;  zz = b1 ? -zz : zz;
    tr += qp<1>(tr); tr += qp<2>(tr);
    ti += qp<1>(ti); ti += qp<2>(ti);
    zz += qp<1>(zz); zz += qp<2>(zz);
    res[1] = 2.f * tr; res[7] = 2.f * ti; res[13] = zz;
  }
  {
    float tr, ti, zz;
    meas_reg<8>(sr, si, tr, ti, zz); res[2] = 2.f*tr; res[8]  = 2.f*ti; res[14] = zz;
    meas_reg<4>(sr, si, tr, ti, zz); res[3] = 2.f*tr; res[9]  = 2.f*ti; res[15] = zz;
    meas_reg<2>(sr, si, tr, ti, zz); res[4] = 2.f*tr; res[10] = 2.f*ti; res[16] = zz;
    meas_reg<1>(sr, si, tr, ti, zz); res[5] = 2.f*tr; res[11] = 2.f*ti; res[17] = zz;
  }
  if (l == 0) {
    float* qo = qv_g + (size_t)chunk * 18;
#pragma unroll
    for (int k = 0; k < 18; ++k) qo[k] = res[k];
  }
}

// ---------------------------------------------------------------------------
// k_circ: tier2 (verbatim R10) — reads half-angles stride 126, computes sincos.

__global__ __launch_bounds__(64) void k_circ(const float* __restrict__ csb_g,
                                             float* __restrict__ qv_g)
{
  const int lane  = threadIdx.x;
  const int c     = lane >> 2;
  const int l     = lane & 3;
  const int chunk = blockIdx.x * 16 + c;
  const float* cp = csb_g + (size_t)chunk * 126;
  const int b0 = (l >> 1) & 1;
  const int b1 = l & 1;

  float sr[16], si[16];
#pragma unroll
  for (int r = 0; r < 16; ++r) { sr[r] = 0.f; si[r] = 0.f; }
  sr[0] = (l == 0) ? 1.f : 0.f;

  {
    float gc[6], gs[6];
#pragma unroll
    for (int g = 0; g < 6; ++g) { float th = cp[g]; gc[g] = __cosf(th); gs[g] = __sinf(th); }
    ry_lane<2>(gc[0], b0 ? gs[0] : -gs[0], sr, si);
    ry_lane<1>(gc[1], b1 ? gs[1] : -gs[1], sr, si);
    ry_reg<8>(gc[2], gs[2], sr, si);
    ry_reg<4>(gc[3], gs[3], sr, si);
    ry_reg<2>(gc[4], gs[4], sr, si);
    ry_reg<1>(gc[5], gs[5], sr, si);
  }

  for (int a = 0; a < 4; ++a) {
    const float* pb = cp + 6 + a * 30;
    float gc[30], gs[30];
#pragma unroll
    for (int g = 0; g < 30; ++g) { float th = pb[g]; gc[g] = __cosf(th); gs[g] = __sinf(th); }
    rx_lane<2>(gc[0], gs[0], sr, si);
    ry_lane<2>(gc[1], b0 ? gs[1] : -gs[1], sr, si);
    rz_lane   (gc[2], b0 ? gs[2] : -gs[2], sr, si);
    rx_lane<1>(gc[3], gs[3], sr, si);
    ry_lane<1>(gc[4], b1 ? gs[4] : -gs[4], sr, si);
    rz_lane   (gc[5], b1 ? gs[5] : -gs[5], sr, si);
    rx_reg<8>(gc[6],  gs[6],  sr, si);  ry_reg<8>(gc[7],  gs[7],  sr, si);  rz_reg<8>(gc[8],  gs[8],  sr, si);
    rx_reg<4>(gc[9],  gs[9],  sr, si);  ry_reg<4>(gc[10], gs[10], sr, si);  rz_reg<4>(gc[11], gs[11], sr, si);
    rx_reg<2>(gc[12], gs[12], sr, si);  ry_reg<2>(gc[13], gs[13], sr, si);  rz_reg<2>(gc[14], gs[14], sr, si);
    rx_reg<1>(gc[15], gs[15], sr, si);  ry_reg<1>(gc[16], gs[16], sr, si);  rz_reg<1>(gc[17], gs[17], sr, si);
    { float c2 = b0 ? gc[18] : 1.f, s2 = b0 ? gs[18] : 0.f; rx_lane<1>(c2, s2, sr, si); }
    { float c2 = b1 ? gc[19] : 1.f, s2 = b1 ? gs[19] : 0.f; rx_reg<8>(c2, s2, sr, si); }
    crx_reg_reg<4, 8>(gc[20], gs[20], sr, si);
    crx_reg_reg<2, 4>(gc[21], gs[21], sr, si);
    crx_reg_reg<1, 2>(gc[22], gs[22], sr, si);
    crx_reg_lane<2, 1>(gc[23], gs[23], sr, si);
    crx_reg_reg<2, 1>(gc[24], gs[24], sr, si);
    crx_reg_reg<4, 2>(gc[25], gs[25], sr, si);
    crx_reg_reg<8, 4>(gc[26], gs[26], sr, si);
    crx_reg_lane<1, 8>(gc[27], gs[27], sr, si);
    { float c2 = b1 ? gc[28] : 1.f, s2 = b1 ? gs[28] : 0.f; rx_lane<2>(c2, s2, sr, si); }
    { float c2 = b0 ? gc[29] : 1.f, s2 = b0 ? gs[29] : 0.f; rx_reg<1>(c2, s2, sr, si); }
  }

  float res[18];
  {
    float tr = 0.f, ti = 0.f, zz = 0.f;
#pragma unroll
    for (int r = 0; r < 16; ++r) {
      float pr = qp<2>(sr[r]), pi = qp<2>(si[r]);
      tr = fmaf(sr[r], pr, fmaf(si[r], pi, tr));
      ti = fmaf(sr[r], pi, fmaf(-si[r], pr, ti));
      zz = fmaf(sr[r], sr[r], fmaf(si[r], si[r], zz));
    }
    tr = b0 ? 0.f : tr;  ti = b0 ? 0.f : ti;  zz = b0 ? -zz : zz;
    tr += qp<1>(tr); tr += qp<2>(tr);
    ti += qp<1>(ti); ti += qp<2>(ti);
    zz += qp<1>(zz); zz += qp<2>(zz);
    res[0] = 2.f * tr; res[6] = 2.f * ti; res[12] = zz;
  }
  {
    float tr = 0.f, ti = 0.f, zz = 0.f;
#pragma unroll
    for (int r = 0; r < 16; ++r) {
      float pr = qp<1>(sr[r]), pi = qp<1>(si[r]);
      tr = fmaf(sr[r], pr, fmaf(si[r], pi, tr));
      ti = fmaf(sr[r], pi, fmaf(-si[r], pr, ti));
      zz = fmaf(sr[r], sr[r], fmaf(si[r], si[r], zz));
    }
    tr = b1 ? 0.f : tr;  ti = b1 ? 0.f : ti;  zz = b1 ? -zz : zz;
    tr += qp<1>(tr); tr += qp<2>(tr);
    ti += qp<1>(ti); ti += qp<2>(ti);
    zz += qp<1>(zz); zz += qp<2>(zz);
    res[1] = 2.f * tr; res[7] = 2.f * ti; res[13] = zz;
  }
  {
    float tr, ti, zz;
    meas_reg<8>(sr, si, tr, ti, zz); res[2] = 2.f*tr; res[8]  = 2.f*ti; res[14] = zz;
    meas_reg<4>(sr, si, tr, ti, zz); res[3] = 2.f*tr; res[9]  = 2.f*ti; res[15] = zz;
    meas_reg<2>(sr, si, tr, ti, zz); res[4] = 2.f*tr; res[10] = 2.f*ti; res[16] = zz;
    meas_reg<1>(sr, si, tr, ti, zz); res[5] = 2.f*tr; res[11] = 2.f*ti; res[17] = zz;
  }
  if (l == 0) {
    float* qo = qv_g + (size_t)chunk * 18;
#pragma unroll
    for (int k = 0; k < 18; ++k) qo[k] = res[k];
  }
}

// ---------------------------------------------------------------------------
// k_post: verbatim R8/R10.

__global__ __launch_bounds__(128) void k_post(
    const float* __restrict__ qv_g,
    const float* __restrict__ op_w, const float* __restrict__ op_b,
    const float* __restrict__ ln2_g, const float* __restrict__ ln2_b,
    const float* __restrict__ sa1_w, const float* __restrict__ sa1_b,
    const float* __restrict__ sa2_w, const float* __restrict__ sa2_b,
    float* __restrict__ cf, float* __restrict__ sclb)
{
  __shared__ float cfs[132];
  __shared__ float part1[32];
  __shared__ float red[4];

  const int chunk = blockIdx.x, tid = threadIdx.x, d = tid;
  const int j = tid & 31, sub = tid >> 5;

  float qv[18];
  {
    const float* qpp = qv_g + (size_t)chunk * 18;
#pragma unroll
    for (int k = 0; k < 18; ++k) qv[k] = qpp[k];
  }
  float acc = op_b[d];
#pragma unroll
  for (int k = 0; k < 18; ++k) acc = fmaf(qv[k], op_w[k * kDM + d], acc);

  float v = acc, v2 = acc * acc;
#pragma unroll
  for (int o = 32; o; o >>= 1) { v += __shfl_xor(v, o, 64); v2 += __shfl_xor(v2, o, 64); }
  if ((tid & 63) == 0) { red[tid >> 6] = v; red[2 + (tid >> 6)] = v2; }
  __syncthreads();
  float s1 = red[0] + red[1], s2 = red[2] + red[3];
  float m = s1 * (1.f / kDM);
  float var = s2 * (1.f / kDM) - m * m;
  float xn = fmaf((acc - m) * rsqrtf(var + 1e-5f), ln2_g[d], ln2_b[d]);
  float cfv = fast_silu(xn);
  cf[(size_t)chunk * kDM + d] = cfv;
  cfs[d] = cfv;
  __syncthreads();

  float acc2 = 0.f;
  {
    const float* wp2 = sa1_w + (sub * 32) * 32 + j;
#pragma unroll
    for (int q = 0; q < 8; ++q) {
      float4 hv = *(const float4*)&cfs[sub * 32 + q * 4];
      acc2 = fmaf(hv.x, wp2[(q*4+0)*32], acc2);
      acc2 = fmaf(hv.y, wp2[(q*4+1)*32], acc2);
      acc2 = fmaf(hv.z, wp2[(q*4+2)*32], acc2);
      acc2 = fmaf(hv.w, wp2[(q*4+3)*32], acc2);
    }
  }
  acc2 += __shfl_xor(acc2, 32, 64);
  if (sub == 2) part1[j] = acc2;
  __syncthreads();
  if (tid < 32) {
    float hv = fast_tanh(acc2 + part1[j] + sa1_b[j]) * sa2_w[j];
#pragma unroll
    for (int o = 16; o; o >>= 1) hv += __shfl_xor(hv, o, 64);
    if (j == 0) sclb[chunk] = hv + sa2_b[0];
  }
}

// ---------------------------------------------------------------------------
// k_pool_cf: per-batch 512-thr softmax + pooling + classifier (ran in R6).

__global__ __launch_bounds__(512) void k_pool_cf(
    const float* __restrict__ cf, const float* __restrict__ scl,
    const float* __restrict__ cl1_w, const float* __restrict__ cl1_b,
    const float* __restrict__ cl2_w, const float* __restrict__ cl2_b,
    float* __restrict__ out)
{
  __shared__ float wl[kNCH];
  __shared__ float rep4[4][kDM];
  __shared__ float ulp[8][64];
  __shared__ float ul[64];
  __shared__ float red2[16];
  int b = blockIdx.x, tid = threadIdx.x;
  int idx = tid & 127, wid = tid >> 6;
  float s = scl[b*kNCH + idx];
  float mx = s;
#pragma unroll
  for (int o = 32; o; o >>= 1) mx = fmaxf(mx, __shfl_xor(mx,o,64));
  if ((tid & 63) == 0) red2[wid] = mx;
  __syncthreads();
  mx = fmaxf(red2[0], red2[1]);
  float e = __expf(s - mx);
  float se = e;
#pragma unroll
  for (int o = 32; o; o >>= 1) se += __shfl_xor(se,o,64);
  if ((tid & 63) == 0) red2[8+wid] = se;
  if (tid < kNCH) wl[tid] = e;
  __syncthreads();
  float inv = 1.f/(red2[8]+red2[9]);
  {
    int dd = tid & 127, qq = tid >> 7;
    const float* cfb = cf + (size_t)b*kNCH*kDM + (size_t)qq*32*kDM;
    const float* wlq = wl + qq*32;
    float a0=0,a1=0,a2=0,a3=0;
#pragma unroll 4
    for (int ncc = 0; ncc < 32; ncc += 4) {
      a0 = fmaf(wlq[ncc+0], cfb[(ncc+0)*kDM+dd], a0);
      a1 = fmaf(wlq[ncc+1], cfb[(ncc+1)*kDM+dd], a1);
      a2 = fmaf(wlq[ncc+2], cfb[(ncc+2)*kDM+dd], a2);
      a3 = fmaf(wlq[ncc+3], cfb[(ncc+3)*kDM+dd], a3);
    }
    rep4[qq][dd] = (a0+a1)+(a2+a3);
  }
  __syncthreads();
  {
    int jj = tid & 63, qq = tid >> 6;
    float accp = 0.f;
#pragma unroll
    for (int k = 0; k < 16; ++k) {
      int dd = qq*16 + k;
      float rv = ((rep4[0][dd]+rep4[1][dd])+(rep4[2][dd]+rep4[3][dd]))*inv;
      accp = fmaf(rv, cl1_w[dd*64+jj], accp);
    }
    ulp[qq][jj] = accp;
  }
  __syncthreads();
  if (tid < 64) {
    float acc = cl1_b[tid];
#pragma unroll
    for (int q = 0; q < 8; ++q) acc += ulp[q][tid];
    ul[tid] = fast_silu(acc);
  }
  __syncthreads();
  if (tid < 2) {
    float acc = cl2_b[tid];
#pragma unroll
    for (int k = 0; k < 64; ++k) acc = fmaf(ul[k], cl2_w[k*2+tid], acc);
    out[b*2+tid] = acc;
  }
}

// ===========================================================================
// FALLBACK tier3 (ws too small): verbatim R8 fallback pipeline.
// ===========================================================================

__device__ __forceinline__ void fb_rx(float2 cs, int w, int lane, float& ar, float& ai) {
  int m = 1 << (5 - w);
  float pr = __shfl_xor(ar, m, 64), pi = __shfl_xor(ai, m, 64);
  float nr = fmaf(cs.x, ar, cs.y * pi), ni = fmaf(cs.x, ai, -cs.y * pr);
  ar = nr; ai = ni;
}
__device__ __forceinline__ void fb_ry(float2 cs, int w, int lane, float& ar, float& ai) {
  int m = 1 << (5 - w);
  float pr = __shfl_xor(ar, m, 64), pi = __shfl_xor(ai, m, 64);
  float sg = ((lane >> (5 - w)) & 1) ? cs.y : -cs.y;
  float nr = fmaf(cs.x, ar, sg * pr), ni = fmaf(cs.x, ai, sg * pi);
  ar = nr; ai = ni;
}
__device__ __forceinline__ void fb_rz(float2 cs, int w, int lane, float& ar, float& ai) {
  float sp = ((lane >> (5 - w)) & 1) ? cs.y : -cs.y;
  float nr = fmaf(ar, cs.x, -ai * sp), ni = fmaf(ar, sp, ai * cs.x);
  ar = nr; ai = ni;
}
__device__ __forceinline__ void fb_crx(float2 cs, int w0, int w1, int lane, float& ar, float& ai) {
  int m = 1 << (5 - w1);
  float pr = __shfl_xor(ar, m, 64), pi = __shfl_xor(ai, m, 64);
  if ((lane >> (5 - w0)) & 1) {
    float nr = fmaf(cs.x, ar, cs.y * pi), ni = fmaf(cs.x, ai, -cs.y * pr);
    ar = nr; ai = ni;
  }
}
__device__ __forceinline__ void fb_ansatz(const float2* cs, int lane, float& ar, float& ai) {
#pragma unroll
  for (int i = 0; i < kNQ; ++i) {
    fb_rx(cs[3*i+0], i, lane, ar, ai);
    fb_ry(cs[3*i+1], i, lane, ar, ai);
    fb_rz(cs[3*i+2], i, lane, ar, ai);
  }
  int off = 18;
#pragma unroll
  for (int i = 0; i < kNQ; ++i) fb_crx(cs[off++], i, (i+1)%kNQ, lane, ar, ai);
#pragma unroll
  for (int i = kNQ-1; i >= 0; --i) fb_crx(cs[off++], i, (i+5)%kNQ, lane, ar, ai);
}

__global__ __launch_bounds__(128) void k_chunk_fb(
    const float* __restrict__ x,
    const float* __restrict__ conv_w, const float* __restrict__ conv_b,
    const float* __restrict__ ln1_g,  const float* __restrict__ ln1_b,
    const float* __restrict__ ca1_w,  const float* __restrict__ ca1_b,
    const float* __restrict__ ca2_w,  const float* __restrict__ ca2_b,
    const float* __restrict__ pp_w,   const float* __restrict__ pp_b,
    const float* __restrict__ ep_w,   const float* __restrict__ ep_b,
    const float* __restrict__ op_w,   const float* __restrict__ op_b,
    const float* __restrict__ ln2_g,  const float* __restrict__ ln2_b,
    float* __restrict__ cf)
{
  __shared__ float hbuf[kCHUNK][132];
  __shared__ __align__(16) float Bu[512];
  __shared__ float mrow[kCHUNK], irow[kCHUNK];
  __shared__ float red[4];
  float (*xs)[kCHUNK+2] = (float(*)[kCHUNK+2])Bu;
  float (*part)[32] = (float(*)[32])Bu;
  float* summ = Bu; float* wl = Bu + 128; float* qv = Bu + 144;
  float2* csb = (float2*)(Bu + 164);

  const int tid = threadIdx.x, chunk = blockIdx.x;
  const int b = chunk >> 7, nc = chunk & 127, t0 = nc * kCHUNK, d = tid;
  const int j = tid & 31, sub = tid >> 5;

  float w12[12];
  {
    const float4* cw = (const float4*)(conv_w + d*12);
    float4 a0=cw[0],a1=cw[1],a2=cw[2];
    w12[0]=a0.x;w12[1]=a0.y;w12[2]=a0.z;w12[3]=a0.w;
    w12[4]=a1.x;w12[5]=a1.y;w12[6]=a1.z;w12[7]=a1.w;
    w12[8]=a2.x;w12[9]=a2.y;w12[10]=a2.z;w12[11]=a2.w;
  }
  float cb = conv_b[d], g1 = ln1_g[d], b1 = ln1_b[d];
  float wreg[32];
  { const float* wp = ca1_w + (sub*32)*32 + j;
#pragma unroll
    for (int k = 0; k < 32; ++k) wreg[k] = wp[k*32]; }

  if (tid < kCH*(kCHUNK+2)) {
    int ch = tid/(kCHUNK+2), pos = tid%(kCHUNK+2), s = t0-1+pos;
    float v = 0.f; if (s >= 0 && s < kSEQ) v = x[(b*kCH+ch)*kSEQ + s];
    xs[ch][pos] = v;
  }
  __syncthreads();
#pragma unroll
  for (int t = 0; t < kCHUNK; ++t) {
    float acc = cb;
#pragma unroll
    for (int ch = 0; ch < kCH; ++ch)
#pragma unroll
      for (int k = 0; k < 3; ++k) acc = fmaf(xs[ch][t+k], w12[ch*3+k], acc);
    hbuf[t][d] = acc;
  }
  __syncthreads();
  {
    int row = tid >> 3, k = tid & 7;
    const float4* rp = (const float4*)&hbuf[row][k*16];
    float s1 = 0.f, s2 = 0.f;
#pragma unroll
    for (int q = 0; q < 4; ++q) {
      float4 v = rp[q];
      s1 += v.x+v.y+v.z+v.w;
      s2 = fmaf(v.x,v.x,s2); s2 = fmaf(v.y,v.y,s2);
      s2 = fmaf(v.z,v.z,s2); s2 = fmaf(v.w,v.w,s2);
    }
#pragma unroll
    for (int o = 1; o < 8; o <<= 1) { s1 += __shfl_xor(s1,o,64); s2 += __shfl_xor(s2,o,64); }
    if (k == 0) {
      float m = s1*(1.f/kDM);
      mrow[row] = m; irow[row] = rsqrtf(s2*(1.f/kDM) - m*m + 1e-5f);
    }
  }
  __syncthreads();
#pragma unroll
  for (int t = 0; t < kCHUNK; ++t)
    hbuf[t][d] = fmaf((hbuf[t][d]-mrow[t])*irow[t], g1, b1);
  __syncthreads();
  float p[kCHUNK];
#pragma unroll
  for (int t = 0; t < kCHUNK; ++t) {
    float acc = 0.f;
#pragma unroll
    for (int qq = 0; qq < 8; ++qq) {
      int q = (qq + 2*sub) & 7;
      float4 v = *(const float4*)&hbuf[t][sub*32 + q*4];
      acc = fmaf(v.x,wreg[q*4+0],acc); acc = fmaf(v.y,wreg[q*4+1],acc);
      acc = fmaf(v.z,wreg[q*4+2],acc); acc = fmaf(v.w,wreg[q*4+3],acc);
    }
    p[t] = acc;
  }
#pragma unroll
  for (int t = 0; t < kCHUNK; ++t) p[t] += __shfl_xor(p[t], 32, 64);
  if (sub == 2) {
#pragma unroll
    for (int t = 0; t < kCHUNK; ++t) part[t][j] = p[t];
  }
  __syncthreads();
  if (tid < 64) {
    float bj = ca1_b[j], w2 = ca2_w[j];
#pragma unroll
    for (int t = 0; t < kCHUNK; ++t) p[t] = fast_tanh(p[t] + part[t][j] + bj) * w2;
#pragma unroll
    for (int o = 16; o; o >>= 1)
#pragma unroll
      for (int t = 0; t < kCHUNK; ++t) p[t] += __shfl_xor(p[t], o, 64);
    float mx = p[0];
#pragma unroll
    for (int t = 1; t < kCHUNK; ++t) mx = fmaxf(mx, p[t]);
    float e[kCHUNK], ssum = 0.f;
#pragma unroll
    for (int t = 0; t < kCHUNK; ++t) { e[t] = __expf(p[t]-mx); ssum += e[t]; }
    float inv = 1.f/ssum;
    if (tid == 0) {
      float4* w4 = (float4*)wl;
      w4[0]=make_float4(e[0]*inv,e[1]*inv,e[2]*inv,e[3]*inv);
      w4[1]=make_float4(e[4]*inv,e[5]*inv,e[6]*inv,e[7]*inv);
      w4[2]=make_float4(e[8]*inv,e[9]*inv,e[10]*inv,e[11]*inv);
      w4[3]=make_float4(e[12]*inv,e[13]*inv,e[14]*inv,e[15]*inv);
    }
  }
  __syncthreads();
  {
    float acc = 0.f;
    const float4* w4 = (const float4*)wl;
#pragma unroll
    for (int tq = 0; tq < 4; ++tq) {
      float4 wv = w4[tq];
      acc = fmaf(wv.x,hbuf[tq*4+0][d],acc); acc = fmaf(wv.y,hbuf[tq*4+1][d],acc);
      acc = fmaf(wv.z,hbuf[tq*4+2][d],acc); acc = fmaf(wv.w,hbuf[tq*4+3][d],acc);
    }
    summ[d] = acc;
  }
  __syncthreads();
  if (tid < kNP) {
    float acc = pp_b[tid];
    const float4* s4 = (const float4*)summ;
#pragma unroll 8
    for (int q = 0; q < 32; ++q) {
      float4 v = s4[q];
      acc = fmaf(v.x,pp_w[(q*4+0)*kNP+tid],acc); acc = fmaf(v.y,pp_w[(q*4+1)*kNP+tid],acc);
      acc = fmaf(v.z,pp_w[(q*4+2)*kNP+tid],acc); acc = fmaf(v.w,pp_w[(q*4+3)*kNP+tid],acc);
    }
    csb[6+tid] = make_float2(__cosf(0.5f*acc), __sinf(0.5f*acc));
  } else if (tid < kNP + kNQ) {
    int jj = tid - kNP;
    float acc = ep_b[jj];
    for (int dd = 0; dd < kDM; ++dd) acc = fmaf(summ[dd], ep_w[dd*kNQ+jj], acc);
    float a = fast_tanh(acc) * kPI;
    csb[jj] = make_float2(__cosf(0.5f*a), __sinf(0.5f*a));
  }
  float ow[18];
#pragma unroll
  for (int jj = 0; jj < 18; ++jj) ow[jj] = op_w[jj*kDM + d];
  float g2 = ln2_g[d], b2 = ln2_b[d], ob = op_b[d];
  __syncthreads();
  if (tid < 64) {
    int lane = tid;
    float ar = (lane == 0) ? 1.f : 0.f, ai = 0.f;
#pragma unroll
    for (int i = 0; i < kNQ; ++i) fb_ry(csb[i], i, lane, ar, ai);
    fb_ansatz(csb+6, lane, ar, ai);  fb_ansatz(csb+36, lane, ar, ai);
    fb_ansatz(csb+66, lane, ar, ai); fb_ansatz(csb+96, lane, ar, ai);
#pragma unroll
    for (int i = 0; i < kNQ; ++i) {
      int m = 1 << (5-i);
      float pr = __shfl_xor(ar, m, 64), pi = __shfl_xor(ai, m, 64);
      int bit = (lane >> (5-i)) & 1;
      float nrm = fmaf(ar,ar,ai*ai);
      float abr, abi, zz;
      if (bit) { abr = 0.f; abi = 0.f; zz = -nrm; }
      else { abr = fmaf(ar,pr,ai*pi); abi = fmaf(ar,pi,-ai*pr); zz = nrm; }
#pragma unroll
      for (int o = 32; o; o >>= 1) {
        abr += __shfl_xor(abr,o,64); abi += __shfl_xor(abi,o,64); zz += __shfl_xor(zz,o,64);
      }
      if (lane == 0) { qv[i] = 2.f*abr; qv[kNQ+i] = 2.f*abi; qv[2*kNQ+i] = zz; }
    }
  }
  __syncthreads();
  {
    float acc = ob;
#pragma unroll
    for (int jj = 0; jj < 18; ++jj) acc = fmaf(qv[jj], ow[jj], acc);
    float v = acc, v2 = acc*acc;
#pragma unroll
    for (int o = 32; o; o >>= 1) { v += __shfl_xor(v,o,64); v2 += __shfl_xor(v2,o,64); }
    if ((tid & 63) == 0) { red[tid>>6] = v; red[2+(tid>>6)] = v2; }
    __syncthreads();
    float s1 = red[0]+red[1], s2 = red[2]+red[3];
    float m = s1*(1.f/kDM), var = s2*(1.f/kDM) - m*m;
    float xn = fmaf((acc-m)*rsqrtf(var+1e-5f), g2, b2);
    cf[(size_t)chunk*kDM + d] = fast_silu(xn);
  }
}

__global__ __launch_bounds__(256) void k_scl_fb(
    const float* __restrict__ cf,
    const float* __restrict__ sa1_w, const float* __restrict__ sa1_b,
    const float* __restrict__ sa2_w, const float* __restrict__ sa2_b,
    float* __restrict__ scl)
{
  int tid = threadIdx.x, wid = tid >> 6, lane = tid & 63;
  int pair = blockIdx.x * 4 + wid;
  int j = lane & 31, hh = lane >> 5;
  const float4* row = (const float4*)(cf + (size_t)pair*kDM + hh*64);
  const float* wp = sa1_w + (hh*64)*32 + j;
  float acc = 0.f;
#pragma unroll
  for (int q = 0; q < 16; ++q) {
    float4 v = row[q];
    acc = fmaf(v.x,wp[(q*4+0)*32],acc); acc = fmaf(v.y,wp[(q*4+1)*32],acc);
    acc = fmaf(v.z,wp[(q*4+2)*32],acc); acc = fmaf(v.w,wp[(q*4+3)*32],acc);
  }
  acc += __shfl_xor(acc, 32, 64);
  float hv = fast_tanh(acc + sa1_b[j]);
  float v = hv * sa2_w[j];
#pragma unroll
  for (int o = 16; o; o >>= 1) v += __shfl_xor(v, o, 64);
  if (lane == 0) scl[pair] = v + sa2_b[0];
}

// ---------------------------------------------------------------------------

extern "C" void kernel_launch(void* const* d_in, const int* in_sizes, int n_in,
                              void* d_out, int out_size, void* d_ws, size_t ws_size,
                              hipStream_t stream) {
  const float* x      = (const float*)d_in[0];
  const float* conv_w = (const float*)d_in[1];
  const float* conv_b = (const float*)d_in[2];
  const float* ln1_g  = (const float*)d_in[3];
  const float* ln1_b  = (const float*)d_in[4];
  const float* ca1_w  = (const float*)d_in[5];
  const float* ca1_b  = (const float*)d_in[6];
  const float* ca2_w  = (const float*)d_in[7];
  const float* ca2_b  = (const float*)d_in[8];
  const float* pp_w   = (const float*)d_in[9];
  const float* pp_b   = (const float*)d_in[10];
  const float* ep_w   = (const float*)d_in[11];
  const float* ep_b   = (const float*)d_in[12];
  const float* op_w   = (const float*)d_in[13];
  const float* op_b   = (const float*)d_in[14];
  const float* ln2_g  = (const float*)d_in[15];
  const float* ln2_b  = (const float*)d_in[16];
  const float* sa1_w  = (const float*)d_in[17];
  const float* sa1_b  = (const float*)d_in[18];
  const float* sa2_w  = (const float*)d_in[19];
  const float* sa2_b  = (const float*)d_in[20];
  const float* cl1_w  = (const float*)d_in[21];
  const float* cl1_b  = (const float*)d_in[22];
  const float* cl2_w  = (const float*)d_in[23];
  const float* cl2_b  = (const float*)d_in[24];
  float* out = (float*)d_out;

  const size_t nch   = (size_t)kBATCH * kNCH;  // 16384
  const size_t fCS   = nch * 256;              // cs pairs; cf aliased at base
  const size_t need1 = (fCS + nch * 18 + nch) * sizeof(float);   // 18.0 MB
  const size_t fA    = nch * kDM;
  const size_t need2 = (fA + nch * 18 + nch) * sizeof(float);    // 9.5 MB

  if (ws_size >= need1) {
    // tier1: csA dead after k_circ_cs; cf (base) lives after k_post.
    float* csA   = (float*)d_ws;
    float* cf    = csA;
    float* qv_g  = csA + fCS;
    float* sclb  = qv_g + nch * 18;
    k_pre8<<<(kBATCH * kNCH) / 8, 128, 0, stream>>>(
        x, conv_w, conv_b, ln1_g, ln1_b, ca1_w, ca1_b, ca2_w, ca2_b,
        pp_w, pp_b, ep_w, ep_b, csA, 1);
    k_circ_cs<<<(kBATCH * kNCH) / 16, 64, 0, stream>>>(csA, qv_g);
    k_post<<<kBATCH * kNCH, 128, 0, stream>>>(
        qv_g, op_w, op_b, ln2_g, ln2_b, sa1_w, sa1_b, sa2_w, sa2_b, cf, sclb);
    k_pool_cf<<<kBATCH, 512, 0, stream>>>(
        cf, sclb, cl1_w, cl1_b, cl2_w, cl2_b, out);
  } else if (ws_size >= need2) {
    // tier2: half-angles; k_circ computes sincos, pool fused.
    float* A     = (float*)d_ws;
    float* qv_g  = A + fA;
    float* sclb  = qv_g + nch * 18;
    k_pre8<<<(kBATCH * kNCH) / 8, 128, 0, stream>>>(
        x, conv_w, conv_b, ln1_g, ln1_b, ca1_w, ca1_b, ca2_w, ca2_b,
        pp_w, pp_b, ep_w, ep_b, A, 0);
    k_circ<<<(kBATCH * kNCH) / 16, 64, 0, stream>>>(A, qv_g);
    k_post<<<kBATCH * kNCH, 128, 0, stream>>>(
        qv_g, op_w, op_b, ln2_g, ln2_b, sa1_w, sa1_b, sa2_w, sa2_b, A, sclb);
    k_pool_cf<<<kBATCH, 512, 0, stream>>>(
        A, sclb, cl1_w, cl1_b, cl2_w, cl2_b, out);
  } else {
    // tier3: R8 fallback.
    float* cf   = (float*)d_ws;
    float* sclb = cf + nch * kDM;
    k_chunk_fb<<<kBATCH * kNCH, 128, 0, stream>>>(
        x, conv_w, conv_b, ln1_g, ln1_b, ca1_w, ca1_b, ca2_w, ca2_b,
        pp_w, pp_b, ep_w, ep_b, op_w, op_b, ln2_g, ln2_b, cf);
    k_scl_fb<<<(kBATCH * kNCH) / 4, 256, 0, stream>>>(cf, sa1_w, sa1_b, sa2_w, sa2_b, sclb);
    k_pool_cf<<<kBATCH, 512, 0, stream>>>(cf, sclb, cl1_w, cl1_b, cl2_w, cl2_b, out);
  }
}

// Round 2
// 191.200 us; speedup vs baseline: 1.1778x; 1.0889x over previous
//
#include <hip/hip_runtime.h>
#include <math.h>

// ---------------------------------------------------------------------------
// QuantumTransformerE2E on MI355X — R14.
// R13 (208 µs; k_pre8 65.5) + tail fusion:
//  * NEW tier0: k_circ_cs + k_post fused into k_circ_post (grid 1024, 256 thr).
//    - wave 0: circuit for 16 chunks (verbatim math via circ_from_cs), qv -> LDS
//    - all 4 waves: k_post math, 8 chunks per 128-thread slot; op_w/sa1_w/LN2
//      loaded once per block (was once per chunk-block: ~165 MB L2 -> ~10 MB)
//    - removes qv_g global round-trip + one launch boundary (4 kernels -> 3)
//    - cf no longer aliases csA (cross-block WAR race) -> tier0 needs 25.3 MB ws
//  * k_pre8 FROZEN (verbatim R13) for clean A/B attribution of the tail change.
//  * tier1 (R13 exact path), tier2, tier3 kept as fallbacks.
// ---------------------------------------------------------------------------

constexpr int kNQ    = 6;
constexpr int kDM    = 128;
constexpr int kCH    = 4;
constexpr int kSEQ   = 2048;
constexpr int kCHUNK = 16;
constexpr int kBATCH = 128;
constexpr int kNCH   = kSEQ / kCHUNK;  // 128
constexpr int kNP    = 120;
constexpr float kPI  = 3.14159265358979323846f;

typedef __attribute__((ext_vector_type(8))) short bf16x8;
typedef __attribute__((ext_vector_type(4))) float f32x4;

__device__ __forceinline__ float fast_tanh(float x) {
  float e = __expf(-2.f * fabsf(x));
  float r = (1.f - e) * __builtin_amdgcn_rcpf(1.f + e);
  return copysignf(r, x);
}
__device__ __forceinline__ float fast_silu(float x) {
  return x * __builtin_amdgcn_rcpf(1.f + __expf(-x));
}

// quad_perm DPP helpers (VALU pipe).
template <int XM>
__device__ __forceinline__ float qp(float v) {
  constexpr int ctrl = (XM == 1) ? 0xB1 : 0x4E;
  return __int_as_float(
      __builtin_amdgcn_update_dpp(0, __float_as_int(v), ctrl, 0xF, 0xF, true));
}

// ---- register-resident 6-qubit gates (verified R8/R10) ---------------------

template <int RB>
__device__ __forceinline__ void rx_reg(float c, float s, float* sr, float* si) {
#pragma unroll
  for (int r0 = 0; r0 < 16; ++r0) {
    if (r0 & RB) continue;
    int r1 = r0 | RB;
    float ar = sr[r0], ai = si[r0], br = sr[r1], bi = si[r1];
    sr[r0] = fmaf(c, ar,  s * bi);  si[r0] = fmaf(c, ai, -s * br);
    sr[r1] = fmaf(c, br,  s * ai);  si[r1] = fmaf(c, bi, -s * ar);
  }
}

template <int RB>
__device__ __forceinline__ void ry_reg(float c, float s, float* sr, float* si) {
#pragma unroll
  for (int r0 = 0; r0 < 16; ++r0) {
    if (r0 & RB) continue;
    int r1 = r0 | RB;
    float ar = sr[r0], ai = si[r0], br = sr[r1], bi = si[r1];
    sr[r0] = fmaf(c, ar, -s * br);  si[r0] = fmaf(c, ai, -s * bi);
    sr[r1] = fmaf(s, ar,  c * br);  si[r1] = fmaf(s, ai,  c * bi);
  }
}

template <int RB>
__device__ __forceinline__ void rz_reg(float c, float s, float* sr, float* si) {
#pragma unroll
  for (int r = 0; r < 16; ++r) {
    float sp = (r & RB) ? s : -s;
    float ar = sr[r], ai = si[r];
    sr[r] = fmaf(c, ar, -sp * ai);
    si[r] = fmaf(c, ai,  sp * ar);
  }
}

template <int XM>
__device__ __forceinline__ void rx_lane(float c, float s, float* sr, float* si) {
#pragma unroll
  for (int r = 0; r < 16; ++r) {
    float pr = qp<XM>(sr[r]), pi = qp<XM>(si[r]);
    sr[r] = fmaf(c, sr[r],  s * pi);
    si[r] = fmaf(c, si[r], -s * pr);
  }
}

template <int XM>
__device__ __forceinline__ void ry_lane(float c, float sg, float* sr, float* si) {
#pragma unroll
  for (int r = 0; r < 16; ++r) {
    float pr = qp<XM>(sr[r]), pi = qp<XM>(si[r]);
    sr[r] = fmaf(c, sr[r], sg * pr);
    si[r] = fmaf(c, si[r], sg * pi);
  }
}

__device__ __forceinline__ void rz_lane(float c, float sp, float* sr, float* si) {
#pragma unroll
  for (int r = 0; r < 16; ++r) {
    float ar = sr[r], ai = si[r];
    sr[r] = fmaf(c, ar, -sp * ai);
    si[r] = fmaf(c, ai,  sp * ar);
  }
}

template <int RB, int CB>
__device__ __forceinline__ void crx_reg_reg(float c, float s, float* sr, float* si) {
#pragma unroll
  for (int r0 = 0; r0 < 16; ++r0) {
    if ((r0 & RB) || !(r0 & CB)) continue;
    int r1 = r0 | RB;
    float ar = sr[r0], ai = si[r0], br = sr[r1], bi = si[r1];
    sr[r0] = fmaf(c, ar,  s * bi);  si[r0] = fmaf(c, ai, -s * br);
    sr[r1] = fmaf(c, br,  s * ai);  si[r1] = fmaf(c, bi, -s * ar);
  }
}

template <int XM, int CB>
__device__ __forceinline__ void crx_reg_lane(float c, float s, float* sr, float* si) {
#pragma unroll
  for (int r = 0; r < 16; ++r) {
    if (!(r & CB)) continue;
    float pr = qp<XM>(sr[r]), pi = qp<XM>(si[r]);
    sr[r] = fmaf(c, sr[r],  s * pi);
    si[r] = fmaf(c, si[r], -s * pr);
  }
}

template <int RB>
__device__ __forceinline__ void meas_reg(const float* sr, const float* si,
                                         float& tr, float& ti, float& zz) {
  tr = 0.f; ti = 0.f; zz = 0.f;
#pragma unroll
  for (int r0 = 0; r0 < 16; ++r0) {
    float n = fmaf(sr[r0], sr[r0], si[r0] * si[r0]);
    zz += (r0 & RB) ? -n : n;
    if (r0 & RB) continue;
    int r1 = r0 | RB;
    tr = fmaf(sr[r0], sr[r1], fmaf(si[r0], si[r1], tr));
    ti = fmaf(sr[r0], si[r1], fmaf(-si[r0], sr[r1], ti));
  }
  tr += qp<1>(tr); tr += qp<2>(tr);
  ti += qp<1>(ti); ti += qp<2>(ti);
  zz += qp<1>(zz); zz += qp<2>(zz);
}

// ---------------------------------------------------------------------------
// circ_from_cs: full 6-qubit circuit from (cos,sin) pairs. Verbatim extraction
// of the R12-verified k_circ_cs compute body. cp = chunk's 128 float2 pairs.
// l in [0,4): lane-within-chunk; b0=(l>>1)&1, b1=l&1. res[18] out.

__device__ __forceinline__ void circ_from_cs(const float2* __restrict__ cp,
                                             int l, int b0, int b1,
                                             float* __restrict__ res) {
  float sr[16], si[16];
#pragma unroll
  for (int r = 0; r < 16; ++r) { sr[r] = 0.f; si[r] = 0.f; }
  sr[0] = (l == 0) ? 1.f : 0.f;

  {
    float2 q0 = cp[0], q1 = cp[1], q2 = cp[2], q3 = cp[3], q4 = cp[4], q5 = cp[5];
    ry_lane<2>(q0.x, b0 ? q0.y : -q0.y, sr, si);
    ry_lane<1>(q1.x, b1 ? q1.y : -q1.y, sr, si);
    ry_reg<8>(q2.x, q2.y, sr, si);
    ry_reg<4>(q3.x, q3.y, sr, si);
    ry_reg<2>(q4.x, q4.y, sr, si);
    ry_reg<1>(q5.x, q5.y, sr, si);
  }

  for (int a = 0; a < 4; ++a) {
    const float2* pb = cp + 6 + a * 30;
    float2 t;
    t = pb[0];  rx_lane<2>(t.x, t.y, sr, si);
    t = pb[1];  ry_lane<2>(t.x, b0 ? t.y : -t.y, sr, si);
    t = pb[2];  rz_lane   (t.x, b0 ? t.y : -t.y, sr, si);
    t = pb[3];  rx_lane<1>(t.x, t.y, sr, si);
    t = pb[4];  ry_lane<1>(t.x, b1 ? t.y : -t.y, sr, si);
    t = pb[5];  rz_lane   (t.x, b1 ? t.y : -t.y, sr, si);
    t = pb[6];  rx_reg<8>(t.x, t.y, sr, si);
    t = pb[7];  ry_reg<8>(t.x, t.y, sr, si);
    t = pb[8];  rz_reg<8>(t.x, t.y, sr, si);
    t = pb[9];  rx_reg<4>(t.x, t.y, sr, si);
    t = pb[10]; ry_reg<4>(t.x, t.y, sr, si);
    t = pb[11]; rz_reg<4>(t.x, t.y, sr, si);
    t = pb[12]; rx_reg<2>(t.x, t.y, sr, si);
    t = pb[13]; ry_reg<2>(t.x, t.y, sr, si);
    t = pb[14]; rz_reg<2>(t.x, t.y, sr, si);
    t = pb[15]; rx_reg<1>(t.x, t.y, sr, si);
    t = pb[16]; ry_reg<1>(t.x, t.y, sr, si);
    t = pb[17]; rz_reg<1>(t.x, t.y, sr, si);
    t = pb[18]; { float c2 = b0 ? t.x : 1.f, s2 = b0 ? t.y : 0.f; rx_lane<1>(c2, s2, sr, si); }
    t = pb[19]; { float c2 = b1 ? t.x : 1.f, s2 = b1 ? t.y : 0.f; rx_reg<8>(c2, s2, sr, si); }
    t = pb[20]; crx_reg_reg<4, 8>(t.x, t.y, sr, si);
    t = pb[21]; crx_reg_reg<2, 4>(t.x, t.y, sr, si);
    t = pb[22]; crx_reg_reg<1, 2>(t.x, t.y, sr, si);
    t = pb[23]; crx_reg_lane<2, 1>(t.x, t.y, sr, si);
    t = pb[24]; crx_reg_reg<2, 1>(t.x, t.y, sr, si);
    t = pb[25]; crx_reg_reg<4, 2>(t.x, t.y, sr, si);
    t = pb[26]; crx_reg_reg<8, 4>(t.x, t.y, sr, si);
    t = pb[27]; crx_reg_lane<1, 8>(t.x, t.y, sr, si);
    t = pb[28]; { float c2 = b1 ? t.x : 1.f, s2 = b1 ? t.y : 0.f; rx_lane<2>(c2, s2, sr, si); }
    t = pb[29]; { float c2 = b0 ? t.x : 1.f, s2 = b0 ? t.y : 0.f; rx_reg<1>(c2, s2, sr, si); }
  }

  {
    float tr = 0.f, ti = 0.f, zz = 0.f;
#pragma unroll
    for (int r = 0; r < 16; ++r) {
      float pr = qp<2>(sr[r]), pi = qp<2>(si[r]);
      tr = fmaf(sr[r], pr, fmaf(si[r], pi, tr));
      ti = fmaf(sr[r], pi, fmaf(-si[r], pr, ti));
      zz = fmaf(sr[r], sr[r], fmaf(si[r], si[r], zz));
    }
    tr = b0 ? 0.f : tr;  ti = b0 ? 0.f : ti;  zz = b0 ? -zz : zz;
    tr += qp<1>(tr); tr += qp<2>(tr);
    ti += qp<1>(ti); ti += qp<2>(ti);
    zz += qp<1>(zz); zz += qp<2>(zz);
    res[0] = 2.f * tr; res[6] = 2.f * ti; res[12] = zz;
  }
  {
    float tr = 0.f, ti = 0.f, zz = 0.f;
#pragma unroll
    for (int r = 0; r < 16; ++r) {
      float pr = qp<1>(sr[r]), pi = qp<1>(si[r]);
      tr = fmaf(sr[r], pr, fmaf(si[r], pi, tr));
      ti = fmaf(sr[r], pi, fmaf(-si[r], pr, ti));
      zz = fmaf(sr[r], sr[r], fmaf(si[r], si[r], zz));
    }
    tr = b1 ? 0.f : tr;  ti = b1 ? 0.f : ti;  zz = b1 ? -zz : zz;
    tr += qp<1>(tr); tr += qp<2>(tr);
    ti += qp<1>(ti); ti += qp<2>(ti);
    zz += qp<1>(zz); zz += qp<2>(zz);
    res[1] = 2.f * tr; res[7] = 2.f * ti; res[13] = zz;
  }
  {
    float tr, ti, zz;
    meas_reg<8>(sr, si, tr, ti, zz); res[2] = 2.f*tr; res[8]  = 2.f*ti; res[14] = zz;
    meas_reg<4>(sr, si, tr, ti, zz); res[3] = 2.f*tr; res[9]  = 2.f*ti; res[15] = zz;
    meas_reg<2>(sr, si, tr, ti, zz); res[4] = 2.f*tr; res[10] = 2.f*ti; res[16] = zz;
    meas_reg<1>(sr, si, tr, ti, zz); res[5] = 2.f*tr; res[11] = 2.f*ti; res[17] = zz;
  }
}

// ---------------------------------------------------------------------------
// k_pre8: VERBATIM R13. conv + LN1 + MFMA chunk attention + batched projections.

__global__ __launch_bounds__(128) void k_pre8(
    const float* __restrict__ x,
    const float* __restrict__ conv_w, const float* __restrict__ conv_b,
    const float* __restrict__ ln1_g,  const float* __restrict__ ln1_b,
    const float* __restrict__ ca1_w,  const float* __restrict__ ca1_b,
    const float* __restrict__ ca2_w,  const float* __restrict__ ca2_b,
    const float* __restrict__ pp_w,   const float* __restrict__ pp_b,
    const float* __restrict__ ep_w,   const float* __restrict__ ep_b,
    float* __restrict__ outb, int emit_cs)
{
  constexpr int NC = 8;  // chunks per block

  __shared__ __align__(16) float xs[kCH][NC * kCHUNK + 4];  // halo'd x segment
  __shared__ __align__(16) float hbuf[kCHUNK][132];
  __shared__ __align__(16) float spart[2][16];
  __shared__ __align__(16) float wl[kCHUNK];
  __shared__ __align__(16) float sums[NC][kDM];
  __shared__ float mrow[kCHUNK], irow[kCHUNK];

  const int tid    = threadIdx.x;
  const int chunk0 = blockIdx.x * NC;
  const int b      = chunk0 >> 7;
  const int tloc   = (chunk0 & 127) * kCHUNK;  // segment start within row
  const int d      = tid;
  const int lane   = tid & 63;
  const int wv     = tid >> 6;
  const int col    = (lane & 15) + 16 * wv;
  const int qd     = lane >> 4;

  // ---- per-block weight setup (once per 8 chunks) ----
  float w12[12];
  {
    const float4* cw = (const float4*)(conv_w + d * 12);
    float4 a0 = cw[0], a1 = cw[1], a2 = cw[2];
    w12[0]=a0.x; w12[1]=a0.y; w12[2]=a0.z; w12[3]=a0.w;
    w12[4]=a1.x; w12[5]=a1.y; w12[6]=a1.z; w12[7]=a1.w;
    w12[8]=a2.x; w12[9]=a2.y; w12[10]=a2.z; w12[11]=a2.w;
  }
  float cb = conv_b[d];
  float g1 = ln1_g[d], b1 = ln1_b[d];
  float cb1 = ca1_b[col], cw2 = ca2_w[col], cb2 = ca2_b[0];

  bf16x8 bhi[4], blo[4];
#pragma unroll
  for (int ks = 0; ks < 4; ++ks)
#pragma unroll
    for (int jj = 0; jj < 8; ++jj) {
      float bvf = ca1_w[(ks * 32 + qd * 8 + jj) * 32 + col];
      unsigned bb = __float_as_uint(bvf);
      bhi[ks][jj] = (short)(bb >> 16);
      float lf = bvf - __uint_as_float(bb & 0xffff0000u);
      blo[ks][jj] = (short)(__float_as_uint(lf) >> 16);
    }

  // ---- stage x segment with halo: positions [tloc-1, tloc+128] ----
#pragma unroll
  for (int ch = 0; ch < kCH; ++ch) {
#pragma unroll
    for (int base = 0; base < 2; ++base) {
      int pos = base * 128 + tid;
      if (pos < NC * kCHUNK + 2) {
        int s = tloc - 1 + pos;
        float v = 0.f;
        if (s >= 0 && s < kSEQ) v = x[((size_t)b * kCH + ch) * kSEQ + s];
        xs[ch][pos] = v;
      }
    }
  }
  __syncthreads();

  for (int c = 0; c < NC; ++c) {
    // ---- conv from LDS (broadcast reads) ----
    float h[kCHUNK];
#pragma unroll
    for (int t = 0; t < kCHUNK; ++t) h[t] = cb;
#pragma unroll
    for (int ch = 0; ch < kCH; ++ch) {
      const float4* xp = (const float4*)&xs[ch][c * kCHUNK];
      float4 v0 = xp[0], v1 = xp[1], v2 = xp[2], v3 = xp[3], v4 = xp[4];
      float xr[18];
      xr[0]=v0.x; xr[1]=v0.y; xr[2]=v0.z; xr[3]=v0.w;
      xr[4]=v1.x; xr[5]=v1.y; xr[6]=v1.z; xr[7]=v1.w;
      xr[8]=v2.x; xr[9]=v2.y; xr[10]=v2.z; xr[11]=v2.w;
      xr[12]=v3.x; xr[13]=v3.y; xr[14]=v3.z; xr[15]=v3.w;
      xr[16]=v4.x; xr[17]=v4.y;
      float c0 = w12[ch*3+0], c1 = w12[ch*3+1], c2 = w12[ch*3+2];
#pragma unroll
      for (int t = 0; t < kCHUNK; ++t)
        h[t] = fmaf(xr[t], c0, fmaf(xr[t+1], c1, fmaf(xr[t+2], c2, h[t])));
    }
#pragma unroll
    for (int t = 0; t < kCHUNK; ++t) hbuf[t][d] = h[t];
    __syncthreads();

    // ---- LN stats ----
    {
      int row = tid >> 3, k = tid & 7;
      const float4* rp = (const float4*)&hbuf[row][k * 16];
      float s1 = 0.f, s2 = 0.f;
#pragma unroll
      for (int q = 0; q < 4; ++q) {
        float4 v = rp[q];
        s1 += v.x + v.y + v.z + v.w;
        s2 = fmaf(v.x,v.x,s2); s2 = fmaf(v.y,v.y,s2);
        s2 = fmaf(v.z,v.z,s2); s2 = fmaf(v.w,v.w,s2);
      }
#pragma unroll
      for (int o = 1; o < 8; o <<= 1) {
        s1 += __shfl_xor(s1, o, 64);
        s2 += __shfl_xor(s2, o, 64);
      }
      if (k == 0) {
        float m = s1 * (1.f / kDM);
        mrow[row] = m;
        irow[row] = rsqrtf(s2 * (1.f / kDM) - m * m + 1e-5f);
      }
    }
    __syncthreads();

    // ---- LN apply + bf16 hi/lo pack into hbuf ----
#pragma unroll
    for (int t = 0; t < kCHUNK; ++t) {
      h[t] = fmaf((h[t] - mrow[t]) * irow[t], g1, b1);
      unsigned hb = __float_as_uint(h[t]);
      float lof = h[t] - __uint_as_float(hb & 0xffff0000u);
      unsigned pk = (hb >> 16) | (__float_as_uint(lof) & 0xffff0000u);
      ((unsigned*)&hbuf[t][0])[d] = pk;
    }
    __syncthreads();

    // ---- MFMA chunk-attention scores ----
    f32x4 acc = {0.f, 0.f, 0.f, 0.f};
    {
      const unsigned* hrow = (const unsigned*)&hbuf[lane & 15][0];
#pragma unroll
      for (int ks = 0; ks < 4; ++ks) {
        const uint4* ap = (const uint4*)(hrow + ks * 32 + qd * 8);
        uint4 w0 = ap[0], w1 = ap[1];
        bf16x8 ahi, alo;
        ahi[0] = (short)(w0.x & 0xffff); ahi[1] = (short)(w0.y & 0xffff);
        ahi[2] = (short)(w0.z & 0xffff); ahi[3] = (short)(w0.w & 0xffff);
        ahi[4] = (short)(w1.x & 0xffff); ahi[5] = (short)(w1.y & 0xffff);
        ahi[6] = (short)(w1.z & 0xffff); ahi[7] = (short)(w1.w & 0xffff);
        alo[0] = (short)(w0.x >> 16); alo[1] = (short)(w0.y >> 16);
        alo[2] = (short)(w0.z >> 16); alo[3] = (short)(w0.w >> 16);
        alo[4] = (short)(w1.x >> 16); alo[5] = (short)(w1.y >> 16);
        alo[6] = (short)(w1.z >> 16); alo[7] = (short)(w1.w >> 16);
        acc = __builtin_amdgcn_mfma_f32_16x16x32_bf16(ahi, bhi[ks], acc, 0, 0, 0);
        acc = __builtin_amdgcn_mfma_f32_16x16x32_bf16(ahi, blo[ks], acc, 0, 0, 0);
        acc = __builtin_amdgcn_mfma_f32_16x16x32_bf16(alo, bhi[ks], acc, 0, 0, 0);
      }
    }

    // ---- tanh + ca2 + reduce over 16 cols -> spart ----
    {
      float ev[4];
#pragma unroll
      for (int r = 0; r < 4; ++r)
        ev[r] = fast_tanh(acc[r] + cb1) * cw2;
#pragma unroll
      for (int o = 1; o < 16; o <<= 1)
#pragma unroll
        for (int r = 0; r < 4; ++r) ev[r] += __shfl_xor(ev[r], o, 64);
      if ((lane & 15) == 0)
        *(float4*)&spart[wv][qd * 4] = make_float4(ev[0], ev[1], ev[2], ev[3]);
    }
    __syncthreads();

    // ---- softmax weights computed once by 16 lanes -> wl ----
    if (tid < 16) {
      float scl = spart[0][tid] + spart[1][tid] + cb2;
      float mx = scl;
#pragma unroll
      for (int o = 1; o < 16; o <<= 1) mx = fmaxf(mx, __shfl_xor(mx, o, 64));
      float e = __expf(scl - mx);
      float se = e;
#pragma unroll
      for (int o = 1; o < 16; o <<= 1) se += __shfl_xor(se, o, 64);
      wl[tid] = e * (1.f / se);
    }
    __syncthreads();

    // ---- weighted pool -> sums[c][d] ----
    {
      const float4* w4 = (const float4*)wl;
      float4 wa = w4[0], wb = w4[1], wc = w4[2], wd = w4[3];
      float acc2 = 0.f;
      acc2 = fmaf(wa.x, h[0],  acc2); acc2 = fmaf(wa.y, h[1],  acc2);
      acc2 = fmaf(wa.z, h[2],  acc2); acc2 = fmaf(wa.w, h[3],  acc2);
      acc2 = fmaf(wb.x, h[4],  acc2); acc2 = fmaf(wb.y, h[5],  acc2);
      acc2 = fmaf(wb.z, h[6],  acc2); acc2 = fmaf(wb.w, h[7],  acc2);
      acc2 = fmaf(wc.x, h[8],  acc2); acc2 = fmaf(wc.y, h[9],  acc2);
      acc2 = fmaf(wc.z, h[10], acc2); acc2 = fmaf(wc.w, h[11], acc2);
      acc2 = fmaf(wd.x, h[12], acc2); acc2 = fmaf(wd.y, h[13], acc2);
      acc2 = fmaf(wd.z, h[14], acc2); acc2 = fmaf(wd.w, h[15], acc2);
      sums[c][d] = acc2;
    }
  }
  __syncthreads();

  // ---- batched pp/ep projection: one weight load feeds 8 chunks ----
  if (tid < kNP + kNQ) {
    const bool isep = (tid >= kNP);
    const int  jj   = tid - kNP;
    const float* wp = isep ? (ep_w + jj) : (pp_w + tid);
    const int  ws   = isep ? kNQ : kNP;
    const int  ws2  = ws * 2, ws3 = ws * 3, ws4 = ws * 4;
    float bias = isep ? ep_b[jj] : pp_b[tid];
    float accp[NC];
#pragma unroll
    for (int c = 0; c < NC; ++c) accp[c] = bias;
#pragma unroll 4
    for (int q4 = 0; q4 < 32; ++q4) {
      float w0 = wp[0], w1 = wp[ws], w2 = wp[ws2], w3 = wp[ws3];
      wp += ws4;
#pragma unroll
      for (int c = 0; c < NC; ++c) {
        float4 s = *(const float4*)&sums[c][q4 * 4];
        accp[c] = fmaf(s.x, w0, fmaf(s.y, w1, fmaf(s.z, w2, fmaf(s.w, w3, accp[c]))));
      }
    }
    const int slot = isep ? jj : (6 + tid);
#pragma unroll
    for (int c = 0; c < NC; ++c) {
      int chunkg = chunk0 + c;
      float ha = isep ? (0.5f * fast_tanh(accp[c]) * kPI) : (0.5f * accp[c]);
      if (emit_cs) {
        ((float2*)(outb + (size_t)chunkg * 256))[slot] =
            make_float2(__cosf(ha), __sinf(ha));
      } else {
        outb[(size_t)chunkg * 126 + slot] = ha;
      }
    }
  }
}

// ---------------------------------------------------------------------------
// k_circ_post: tier0 fused circuit + post. grid 1024 x 256 thr.
// wave 0: circuits for 16 chunks (qv -> LDS). all waves: post for 8 chunks
// per 128-thread slot, weights loaded once per block.

constexpr int kCsStride = 260;  // floats; b128-aligned (1040 B)

__global__ __launch_bounds__(256) void k_circ_post(
    const float* __restrict__ csA,
    const float* __restrict__ op_w, const float* __restrict__ op_b,
    const float* __restrict__ ln2_g, const float* __restrict__ ln2_b,
    const float* __restrict__ sa1_w, const float* __restrict__ sa1_b,
    const float* __restrict__ sa2_w, const float* __restrict__ sa2_b,
    float* __restrict__ cf, float* __restrict__ sclb)
{
  __shared__ __align__(16) float lds[16 * kCsStride];  // 16.6 KB
  __shared__ __align__(16) float qvs[16][19];
  __shared__ __align__(16) float cfs[2][132];
  __shared__ float part1[2][32];
  __shared__ float redA[2][2], redB[2][2];

  const int tid = threadIdx.x;

  // ---- stage 16 chunks' cs pairs with all 256 threads ----
  {
    const float4* src = (const float4*)(csA + (size_t)blockIdx.x * 16 * 256);
#pragma unroll
    for (int jq = 0; jq < 4; ++jq) {
      int idx = jq * 256 + tid;
      int ic = idx >> 6, ln = idx & 63;
      *(float4*)&lds[ic * kCsStride + ln * 4] = src[idx];
    }
  }
  __syncthreads();

  // ---- phase 1: wave 0 computes 16 circuits (no barriers inside) ----
  if (tid < 64) {
    const int c  = tid >> 2;
    const int l  = tid & 3;
    const int b0 = (l >> 1) & 1;
    const int b1 = l & 1;
    float res[18];
    circ_from_cs((const float2*)&lds[c * kCsStride], l, b0, b1, res);
    if (l == 0) {
#pragma unroll
      for (int k = 0; k < 18; ++k) qvs[c][k] = res[k];
    }
  }

  // ---- phase-2 per-thread constants (once per block) ----
  const int d    = tid & 127;
  const int slot = tid >> 7;
  const int j    = d & 31;
  const int sub  = d >> 5;
  float ow[18];
#pragma unroll
  for (int k = 0; k < 18; ++k) ow[k] = op_w[k * kDM + d];
  float ob = op_b[d], g2 = ln2_g[d], b2 = ln2_b[d];
  float wreg[32];
  {
    const float* wp2 = sa1_w + (sub * 32) * 32 + j;
#pragma unroll
    for (int k = 0; k < 32; ++k) wreg[k] = wp2[k * 32];
  }
  float s1b = sa1_b[j], s2w = sa2_w[j], s2b = sa2_b[0];
  __syncthreads();

  // ---- phase 2: k_post math, 8 chunks per slot ----
  for (int i = 0; i < 8; ++i) {
    const int c      = slot * 8 + i;
    const int chunkg = blockIdx.x * 16 + c;

    float qv[18];
#pragma unroll
    for (int k = 0; k < 18; ++k) qv[k] = qvs[c][k];
    float acc = ob;
#pragma unroll
    for (int k = 0; k < 18; ++k) acc = fmaf(qv[k], ow[k], acc);

    float v = acc, v2 = acc * acc;
#pragma unroll
    for (int o = 32; o; o >>= 1) { v += __shfl_xor(v, o, 64); v2 += __shfl_xor(v2, o, 64); }
    if ((d & 63) == 0) { redA[slot][d >> 6] = v; redB[slot][d >> 6] = v2; }
    __syncthreads();
    float ss1 = redA[slot][0] + redA[slot][1];
    float ss2 = redB[slot][0] + redB[slot][1];
    float m = ss1 * (1.f / kDM);
    float var = ss2 * (1.f / kDM) - m * m;
    float xn = fmaf((acc - m) * rsqrtf(var + 1e-5f), g2, b2);
    float cfv = fast_silu(xn);
    cf[(size_t)chunkg * kDM + d] = cfv;
    cfs[slot][d] = cfv;
    __syncthreads();

    float acc2 = 0.f;
#pragma unroll
    for (int q = 0; q < 8; ++q) {
      float4 hv = *(const float4*)&cfs[slot][sub * 32 + q * 4];
      acc2 = fmaf(hv.x, wreg[q*4+0], acc2);
      acc2 = fmaf(hv.y, wreg[q*4+1], acc2);
      acc2 = fmaf(hv.z, wreg[q*4+2], acc2);
      acc2 = fmaf(hv.w, wreg[q*4+3], acc2);
    }
    acc2 += __shfl_xor(acc2, 32, 64);
    if (sub == 2) part1[slot][j] = acc2;
    __syncthreads();
    if (d < 32) {
      float hv = fast_tanh(acc2 + part1[slot][j] + s1b) * s2w;
#pragma unroll
      for (int o = 16; o; o >>= 1) hv += __shfl_xor(hv, o, 64);
      if (j == 0) sclb[chunkg] = hv + s2b;
    }
  }
}

// ---------------------------------------------------------------------------
// k_circ_cs: tier1 (unfused) — LDS-staged (cos,sin), writes qv to global.

__global__ __launch_bounds__(64) void k_circ_cs(const float* __restrict__ csA,
                                                float* __restrict__ qv_g)
{
  __shared__ __align__(16) float lds[16 * kCsStride];  // 16.6 KB

  const int lane  = threadIdx.x;
  const int c     = lane >> 2;
  const int l     = lane & 3;
  const int chunk = blockIdx.x * 16 + c;
  const int b0 = (l >> 1) & 1;
  const int b1 = l & 1;

  {
    const float4* src = (const float4*)(csA + (size_t)blockIdx.x * 16 * 256);
#pragma unroll
    for (int i = 0; i < 16; ++i) {
      float4 v = src[i * 64 + lane];
      *(float4*)&lds[i * kCsStride + lane * 4] = v;
    }
  }
  __syncthreads();

  float res[18];
  circ_from_cs((const float2*)&lds[c * kCsStride], l, b0, b1, res);

  if (l == 0) {
    float* qo = qv_g + (size_t)chunk * 18;
#pragma unroll
    for (int k = 0; k < 18; ++k) qo[k] = res[k];
  }
}

// ---------------------------------------------------------------------------
// k_circ: tier2 — reads half-angles stride 126, computes sincos.

__global__ __launch_bounds__(64) void k_circ(const float* __restrict__ csb_g,
                                             float* __restrict__ qv_g)
{
  const int lane  = threadIdx.x;
  const int c     = lane >> 2;
  const int l     = lane & 3;
  const int chunk = blockIdx.x * 16 + c;
  const float* cp = csb_g + (size_t)chunk * 126;
  const int b0 = (l >> 1) & 1;
  const int b1 = l & 1;

  float sr[16], si[16];
#pragma unroll
  for (int r = 0; r < 16; ++r) { sr[r] = 0.f; si[r] = 0.f; }
  sr[0] = (l == 0) ? 1.f : 0.f;

  {
    float gc[6], gs[6];
#pragma unroll
    for (int g = 0; g < 6; ++g) { float th = cp[g]; gc[g] = __cosf(th); gs[g] = __sinf(th); }
    ry_lane<2>(gc[0], b0 ? gs[0] : -gs[0], sr, si);
    ry_lane<1>(gc[1], b1 ? gs[1] : -gs[1], sr, si);
    ry_reg<8>(gc[2], gs[2], sr, si);
    ry_reg<4>(gc[3], gs[3], sr, si);
    ry_reg<2>(gc[4], gs[4], sr, si);
    ry_reg<1>(gc[5], gs[5], sr, si);
  }

  for (int a = 0; a < 4; ++a) {
    const float* pb = cp + 6 + a * 30;
    float gc[30], gs[30];
#pragma unroll
    for (int g = 0; g < 30; ++g) { float th = pb[g]; gc[g] = __cosf(th); gs[g] = __sinf(th); }
    rx_lane<2>(gc[0], gs[0], sr, si);
    ry_lane<2>(gc[1], b0 ? gs[1] : -gs[1], sr, si);
    rz_lane   (gc[2], b0 ? gs[2] : -gs[2], sr, si);
    rx_lane<1>(gc[3], gs[3], sr, si);
    ry_lane<1>(gc[4], b1 ? gs[4] : -gs[4], sr, si);
    rz_lane   (gc[5], b1 ? gs[5] : -gs[5], sr, si);
    rx_reg<8>(gc[6],  gs[6],  sr, si);  ry_reg<8>(gc[7],  gs[7],  sr, si);  rz_reg<8>(gc[8],  gs[8],  sr, si);
    rx_reg<4>(gc[9],  gs[9],  sr, si);  ry_reg<4>(gc[10], gs[10], sr, si);  rz_reg<4>(gc[11], gs[11], sr, si);
    rx_reg<2>(gc[12], gs[12], sr, si);  ry_reg<2>(gc[13], gs[13], sr, si);  rz_reg<2>(gc[14], gs[14], sr, si);
    rx_reg<1>(gc[15], gs[15], sr, si);  ry_reg<1>(gc[16], gs[16], sr, si);  rz_reg<1>(gc[17], gs[17], sr, si);
    { float c2 = b0 ? gc[18] : 1.f, s2 = b0 ? gs[18] : 0.f; rx_lane<1>(c2, s2, sr, si); }
    { float c2 = b1 ? gc[19] : 1.f, s2 = b1 ? gs[19] : 0.f; rx_reg<8>(c2, s2, sr, si); }
    crx_reg_reg<4, 8>(gc[20], gs[20], sr, si);
    crx_reg_reg<2, 4>(gc[21], gs[21], sr, si);
    crx_reg_reg<1, 2>(gc[22], gs[22], sr, si);
    crx_reg_lane<2, 1>(gc[23], gs[23], sr, si);
    crx_reg_reg<2, 1>(gc[24], gs[24], sr, si);
    crx_reg_reg<4, 2>(gc[25], gs[25], sr, si);
    crx_reg_reg<8, 4>(gc[26], gs[26], sr, si);
    crx_reg_lane<1, 8>(gc[27], gs[27], sr, si);
    { float c2 = b1 ? gc[28] : 1.f, s2 = b1 ? gs[28] : 0.f; rx_lane<2>(c2, s2, sr, si); }
    { float c2 = b0 ? gc[29] : 1.f, s2 = b0 ? gs[29] : 0.f; rx_reg<1>(c2, s2, sr, si); }
  }

  float res[18];
  {
    float tr = 0.f, ti = 0.f, zz = 0.f;
#pragma unroll
    for (int r = 0; r < 16; ++r) {
      float pr = qp<2>(sr[r]), pi = qp<2>(si[r]);
      tr = fmaf(sr[r], pr, fmaf(si[r], pi, tr));
      ti = fmaf(sr[r], pi, fmaf(-si[r], pr, ti));
      zz = fmaf(sr[r], sr[r], fmaf(si[r], si[r], zz));
    }
    tr = b0 ? 0.f : tr;  ti = b0 ? 0.f : ti;  zz = b0 ? -zz : zz;
    tr += qp<1>(tr); tr += qp<2>(tr);
    ti += qp<1>(ti); ti += qp<2>(ti);
    zz += qp<1>(zz); zz += qp<2>(zz);
    res[0] = 2.f * tr; res[6] = 2.f * ti; res[12] = zz;
  }
  {
    float tr = 0.f, ti = 0.f, zz = 0.f;
#pragma unroll
    for (int r = 0; r < 16; ++r) {
      float pr = qp<1>(sr[r]), pi = qp<1>(si[r]);
      tr = fmaf(sr[r], pr, fmaf(si[r], pi, tr));
      ti = fmaf(sr[r], pi, fmaf(-si[r], pr, ti));
      zz = fmaf(sr[r], sr[r], fmaf(si[r], si[r], zz));
    }
    tr = b1 ? 0.f : tr;  ti = b1 ? 0.f : ti;  zz = b1 ? -zz : zz;
    tr += qp<1>(tr); tr += qp<2>(tr);
    ti += qp<1>(ti); ti += qp<2>(ti);
    zz += qp<1>(zz); zz += qp<2>(zz);
    res[1] = 2.f * tr; res[7] = 2.f * ti; res[13] = zz;
  }
  {
    float tr, ti, zz;
    meas_reg<8>(sr, si, tr, ti, zz); res[2] = 2.f*tr; res[8]  = 2.f*ti; res[14] = zz;
    meas_reg<4>(sr, si, tr, ti, zz); res[3] = 2.f*tr; res[9]  = 2.f*ti; res[15] = zz;
    meas_reg<2>(sr, si, tr, ti, zz); res[4] = 2.f*tr; res[10] = 2.f*ti; res[16] = zz;
    meas_reg<1>(sr, si, tr, ti, zz); res[5] = 2.f*tr; res[11] = 2.f*ti; res[17] = zz;
  }
  if (l == 0) {
    float* qo = qv_g + (size_t)chunk * 18;
#pragma unroll
    for (int k = 0; k < 18; ++k) qo[k] = res[k];
  }
}

// ---------------------------------------------------------------------------
// k_post: verbatim R8/R10 (tier1/tier2 path).

__global__ __launch_bounds__(128) void k_post(
    const float* __restrict__ qv_g,
    const float* __restrict__ op_w, const float* __restrict__ op_b,
    const float* __restrict__ ln2_g, const float* __restrict__ ln2_b,
    const float* __restrict__ sa1_w, const float* __restrict__ sa1_b,
    const float* __restrict__ sa2_w, const float* __restrict__ sa2_b,
    float* __restrict__ cf, float* __restrict__ sclb)
{
  __shared__ float cfs[132];
  __shared__ float part1[32];
  __shared__ float red[4];

  const int chunk = blockIdx.x, tid = threadIdx.x, d = tid;
  const int j = tid & 31, sub = tid >> 5;

  float qv[18];
  {
    const float* qpp = qv_g + (size_t)chunk * 18;
#pragma unroll
    for (int k = 0; k < 18; ++k) qv[k] = qpp[k];
  }
  float acc = op_b[d];
#pragma unroll
  for (int k = 0; k < 18; ++k) acc = fmaf(qv[k], op_w[k * kDM + d], acc);

  float v = acc, v2 = acc * acc;
#pragma unroll
  for (int o = 32; o; o >>= 1) { v += __shfl_xor(v, o, 64); v2 += __shfl_xor(v2, o, 64); }
  if ((tid & 63) == 0) { red[tid >> 6] = v; red[2 + (tid >> 6)] = v2; }
  __syncthreads();
  float s1 = red[0] + red[1], s2 = red[2] + red[3];
  float m = s1 * (1.f / kDM);
  float var = s2 * (1.f / kDM) - m * m;
  float xn = fmaf((acc - m) * rsqrtf(var + 1e-5f), ln2_g[d], ln2_b[d]);
  float cfv = fast_silu(xn);
  cf[(size_t)chunk * kDM + d] = cfv;
  cfs[d] = cfv;
  __syncthreads();

  float acc2 = 0.f;
  {
    const float* wp2 = sa1_w + (sub * 32) * 32 + j;
#pragma unroll
    for (int q = 0; q < 8; ++q) {
      float4 hv = *(const float4*)&cfs[sub * 32 + q * 4];
      acc2 = fmaf(hv.x, wp2[(q*4+0)*32], acc2);
      acc2 = fmaf(hv.y, wp2[(q*4+1)*32], acc2);
      acc2 = fmaf(hv.z, wp2[(q*4+2)*32], acc2);
      acc2 = fmaf(hv.w, wp2[(q*4+3)*32], acc2);
    }
  }
  acc2 += __shfl_xor(acc2, 32, 64);
  if (sub == 2) part1[j] = acc2;
  __syncthreads();
  if (tid < 32) {
    float hv = fast_tanh(acc2 + part1[j] + sa1_b[j]) * sa2_w[j];
#pragma unroll
    for (int o = 16; o; o >>= 1) hv += __shfl_xor(hv, o, 64);
    if (j == 0) sclb[chunk] = hv + sa2_b[0];
  }
}

// ---------------------------------------------------------------------------
// k_pool_cf: per-batch 512-thr softmax + pooling + classifier.

__global__ __launch_bounds__(512) void k_pool_cf(
    const float* __restrict__ cf, const float* __restrict__ scl,
    const float* __restrict__ cl1_w, const float* __restrict__ cl1_b,
    const float* __restrict__ cl2_w, const float* __restrict__ cl2_b,
    float* __restrict__ out)
{
  __shared__ float wl[kNCH];
  __shared__ float rep4[4][kDM];
  __shared__ float ulp[8][64];
  __shared__ float ul[64];
  __shared__ float red2[16];
  int b = blockIdx.x, tid = threadIdx.x;
  int idx = tid & 127, wid = tid >> 6;
  float s = scl[b*kNCH + idx];
  float mx = s;
#pragma unroll
  for (int o = 32; o; o >>= 1) mx = fmaxf(mx, __shfl_xor(mx,o,64));
  if ((tid & 63) == 0) red2[wid] = mx;
  __syncthreads();
  mx = fmaxf(red2[0], red2[1]);
  float e = __expf(s - mx);
  float se = e;
#pragma unroll
  for (int o = 32; o; o >>= 1) se += __shfl_xor(se,o,64);
  if ((tid & 63) == 0) red2[8+wid] = se;
  if (tid < kNCH) wl[tid] = e;
  __syncthreads();
  float inv = 1.f/(red2[8]+red2[9]);
  {
    int dd = tid & 127, qq = tid >> 7;
    const float* cfb = cf + (size_t)b*kNCH*kDM + (size_t)qq*32*kDM;
    const float* wlq = wl + qq*32;
    float a0=0,a1=0,a2=0,a3=0;
#pragma unroll 4
    for (int ncc = 0; ncc < 32; ncc += 4) {
      a0 = fmaf(wlq[ncc+0], cfb[(ncc+0)*kDM+dd], a0);
      a1 = fmaf(wlq[ncc+1], cfb[(ncc+1)*kDM+dd], a1);
      a2 = fmaf(wlq[ncc+2], cfb[(ncc+2)*kDM+dd], a2);
      a3 = fmaf(wlq[ncc+3], cfb[(ncc+3)*kDM+dd], a3);
    }
    rep4[qq][dd] = (a0+a1)+(a2+a3);
  }
  __syncthreads();
  {
    int jj = tid & 63, qq = tid >> 6;
    float accp = 0.f;
#pragma unroll
    for (int k = 0; k < 16; ++k) {
      int dd = qq*16 + k;
      float rv = ((rep4[0][dd]+rep4[1][dd])+(rep4[2][dd]+rep4[3][dd]))*inv;
      accp = fmaf(rv, cl1_w[dd*64+jj], accp);
    }
    ulp[qq][jj] = accp;
  }
  __syncthreads();
  if (tid < 64) {
    float acc = cl1_b[tid];
#pragma unroll
    for (int q = 0; q < 8; ++q) acc += ulp[q][tid];
    ul[tid] = fast_silu(acc);
  }
  __syncthreads();
  if (tid < 2) {
    float acc = cl2_b[tid];
#pragma unroll
    for (int k = 0; k < 64; ++k) acc = fmaf(ul[k], cl2_w[k*2+tid], acc);
    out[b*2+tid] = acc;
  }
}

// ===========================================================================
// FALLBACK tier3 (ws too small): verbatim R8 fallback pipeline.
// ===========================================================================

__device__ __forceinline__ void fb_rx(float2 cs, int w, int lane, float& ar, float& ai) {
  int m = 1 << (5 - w);
  float pr = __shfl_xor(ar, m, 64), pi = __shfl_xor(ai, m, 64);
  float nr = fmaf(cs.x, ar, cs.y * pi), ni = fmaf(cs.x, ai, -cs.y * pr);
  ar = nr; ai = ni;
}
__device__ __forceinline__ void fb_ry(float2 cs, int w, int lane, float& ar, float& ai) {
  int m = 1 << (5 - w);
  float pr = __shfl_xor(ar, m, 64), pi = __shfl_xor(ai, m, 64);
  float sg = ((lane >> (5 - w)) & 1) ? cs.y : -cs.y;
  float nr = fmaf(cs.x, ar, sg * pr), ni = fmaf(cs.x, ai, sg * pi);
  ar = nr; ai = ni;
}
__device__ __forceinline__ void fb_rz(float2 cs, int w, int lane, float& ar, float& ai) {
  float sp = ((lane >> (5 - w)) & 1) ? cs.y : -cs.y;
  float nr = fmaf(ar, cs.x, -ai * sp), ni = fmaf(ar, sp, ai * cs.x);
  ar = nr; ai = ni;
}
__device__ __forceinline__ void fb_crx(float2 cs, int w0, int w1, int lane, float& ar, float& ai) {
  int m = 1 << (5 - w1);
  float pr = __shfl_xor(ar, m, 64), pi = __shfl_xor(ai, m, 64);
  if ((lane >> (5 - w0)) & 1) {
    float nr = fmaf(cs.x, ar, cs.y * pi), ni = fmaf(cs.x, ai, -cs.y * pr);
    ar = nr; ai = ni;
  }
}
__device__ __forceinline__ void fb_ansatz(const float2* cs, int lane, float& ar, float& ai) {
#pragma unroll
  for (int i = 0; i < kNQ; ++i) {
    fb_rx(cs[3*i+0], i, lane, ar, ai);
    fb_ry(cs[3*i+1], i, lane, ar, ai);
    fb_rz(cs[3*i+2], i, lane, ar, ai);
  }
  int off = 18;
#pragma unroll
  for (int i = 0; i < kNQ; ++i) fb_crx(cs[off++], i, (i+1)%kNQ, lane, ar, ai);
#pragma unroll
  for (int i = kNQ-1; i >= 0; --i) fb_crx(cs[off++], i, (i+5)%kNQ, lane, ar, ai);
}

__global__ __launch_bounds__(128) void k_chunk_fb(
    const float* __restrict__ x,
    const float* __restrict__ conv_w, const float* __restrict__ conv_b,
    const float* __restrict__ ln1_g,  const float* __restrict__ ln1_b,
    const float* __restrict__ ca1_w,  const float* __restrict__ ca1_b,
    const float* __restrict__ ca2_w,  const float* __restrict__ ca2_b,
    const float* __restrict__ pp_w,   const float* __restrict__ pp_b,
    const float* __restrict__ ep_w,   const float* __restrict__ ep_b,
    const float* __restrict__ op_w,   const float* __restrict__ op_b,
    const float* __restrict__ ln2_g,  const float* __restrict__ ln2_b,
    float* __restrict__ cf)
{
  __shared__ float hbuf[kCHUNK][132];
  __shared__ __align__(16) float Bu[512];
  __shared__ float mrow[kCHUNK], irow[kCHUNK];
  __shared__ float red[4];
  float (*xs)[kCHUNK+2] = (float(*)[kCHUNK+2])Bu;
  float (*part)[32] = (float(*)[32])Bu;
  float* summ = Bu; float* wl = Bu + 128; float* qv = Bu + 144;
  float2* csb = (float2*)(Bu + 164);

  const int tid = threadIdx.x, chunk = blockIdx.x;
  const int b = chunk >> 7, nc = chunk & 127, t0 = nc * kCHUNK, d = tid;
  const int j = tid & 31, sub = tid >> 5;

  float w12[12];
  {
    const float4* cw = (const float4*)(conv_w + d*12);
    float4 a0=cw[0],a1=cw[1],a2=cw[2];
    w12[0]=a0.x;w12[1]=a0.y;w12[2]=a0.z;w12[3]=a0.w;
    w12[4]=a1.x;w12[5]=a1.y;w12[6]=a1.z;w12[7]=a1.w;
    w12[8]=a2.x;w12[9]=a2.y;w12[10]=a2.z;w12[11]=a2.w;
  }
  float cb = conv_b[d], g1 = ln1_g[d], b1 = ln1_b[d];
  float wreg[32];
  { const float* wp = ca1_w + (sub*32)*32 + j;
#pragma unroll
    for (int k = 0; k < 32; ++k) wreg[k] = wp[k*32]; }

  if (tid < kCH*(kCHUNK+2)) {
    int ch = tid/(kCHUNK+2), pos = tid%(kCHUNK+2), s = t0-1+pos;
    float v = 0.f; if (s >= 0 && s < kSEQ) v = x[(b*kCH+ch)*kSEQ + s];
    xs[ch][pos] = v;
  }
  __syncthreads();
#pragma unroll
  for (int t = 0; t < kCHUNK; ++t) {
    float acc = cb;
#pragma unroll
    for (int ch = 0; ch < kCH; ++ch)
#pragma unroll
      for (int k = 0; k < 3; ++k) acc = fmaf(xs[ch][t+k], w12[ch*3+k], acc);
    hbuf[t][d] = acc;
  }
  __syncthreads();
  {
    int row = tid >> 3, k = tid & 7;
    const float4* rp = (const float4*)&hbuf[row][k*16];
    float s1 = 0.f, s2 = 0.f;
#pragma unroll
    for (int q = 0; q < 4; ++q) {
      float4 v = rp[q];
      s1 += v.x+v.y+v.z+v.w;
      s2 = fmaf(v.x,v.x,s2); s2 = fmaf(v.y,v.y,s2);
      s2 = fmaf(v.z,v.z,s2); s2 = fmaf(v.w,v.w,s2);
    }
#pragma unroll
    for (int o = 1; o < 8; o <<= 1) { s1 += __shfl_xor(s1,o,64); s2 += __shfl_xor(s2,o,64); }
    if (k == 0) {
      float m = s1*(1.f/kDM);
      mrow[row] = m; irow[row] = rsqrtf(s2*(1.f/kDM) - m*m + 1e-5f);
    }
  }
  __syncthreads();
#pragma unroll
  for (int t = 0; t < kCHUNK; ++t)
    hbuf[t][d] = fmaf((hbuf[t][d]-mrow[t])*irow[t], g1, b1);
  __syncthreads();
  float p[kCHUNK];
#pragma unroll
  for (int t = 0; t < kCHUNK; ++t) {
    float acc = 0.f;
#pragma unroll
    for (int qq = 0; qq < 8; ++qq) {
      int q = (qq + 2*sub) & 7;
      float4 v = *(const float4*)&hbuf[t][sub*32 + q*4];
      acc = fmaf(v.x,wreg[q*4+0],acc); acc = fmaf(v.y,wreg[q*4+1],acc);
      acc = fmaf(v.z,wreg[q*4+2],acc); acc = fmaf(v.w,wreg[q*4+3],acc);
    }
    p[t] = acc;
  }
#pragma unroll
  for (int t = 0; t < kCHUNK; ++t) p[t] += __shfl_xor(p[t], 32, 64);
  if (sub == 2) {
#pragma unroll
    for (int t = 0; t < kCHUNK; ++t) part[t][j] = p[t];
  }
  __syncthreads();
  if (tid < 64) {
    float bj = ca1_b[j], w2 = ca2_w[j];
#pragma unroll
    for (int t = 0; t < kCHUNK; ++t) p[t] = fast_tanh(p[t] + part[t][j] + bj) * w2;
#pragma unroll
    for (int o = 16; o; o >>= 1)
#pragma unroll
      for (int t = 0; t < kCHUNK; ++t) p[t] += __shfl_xor(p[t], o, 64);
    float mx = p[0];
#pragma unroll
    for (int t = 1; t < kCHUNK; ++t) mx = fmaxf(mx, p[t]);
    float e[kCHUNK], ssum = 0.f;
#pragma unroll
    for (int t = 0; t < kCHUNK; ++t) { e[t] = __expf(p[t]-mx); ssum += e[t]; }
    float inv = 1.f/ssum;
    if (tid == 0) {
      float4* w4 = (float4*)wl;
      w4[0]=make_float4(e[0]*inv,e[1]*inv,e[2]*inv,e[3]*inv);
      w4[1]=make_float4(e[4]*inv,e[5]*inv,e[6]*inv,e[7]*inv);
      w4[2]=make_float4(e[8]*inv,e[9]*inv,e[10]*inv,e[11]*inv);
      w4[3]=make_float4(e[12]*inv,e[13]*inv,e[14]*inv,e[15]*inv);
    }
  }
  __syncthreads();
  {
    float acc = 0.f;
    const float4* w4 = (const float4*)wl;
#pragma unroll
    for (int tq = 0; tq < 4; ++tq) {
      float4 wv = w4[tq];
      acc = fmaf(wv.x,hbuf[tq*4+0][d],acc); acc = fmaf(wv.y,hbuf[tq*4+1][d],acc);
      acc = fmaf(wv.z,hbuf[tq*4+2][d],acc); acc = fmaf(wv.w,hbuf[tq*4+3][d],acc);
    }
    summ[d] = acc;
  }
  __syncthreads();
  if (tid < kNP) {
    float acc = pp_b[tid];
    const float4* s4 = (const float4*)summ;
#pragma unroll 8
    for (int q = 0; q < 32; ++q) {
      float4 v = s4[q];
      acc = fmaf(v.x,pp_w[(q*4+0)*kNP+tid],acc); acc = fmaf(v.y,pp_w[(q*4+1)*kNP+tid],acc);
      acc = fmaf(v.z,pp_w[(q*4+2)*kNP+tid],acc); acc = fmaf(v.w,pp_w[(q*4+3)*kNP+tid],acc);
    }
    csb[6+tid] = make_float2(__cosf(0.5f*acc), __sinf(0.5f*acc));
  } else if (tid < kNP + kNQ) {
    int jj = tid - kNP;
    float acc = ep_b[jj];
    for (int dd = 0; dd < kDM; ++dd) acc = fmaf(summ[dd], ep_w[dd*kNQ+jj], acc);
    float a = fast_tanh(acc) * kPI;
    csb[jj] = make_float2(__cosf(0.5f*a), __sinf(0.5f*a));
  }
  float ow[18];
#pragma unroll
  for (int jj = 0; jj < 18; ++jj) ow[jj] = op_w[jj*kDM + d];
  float g2 = ln2_g[d], b2 = ln2_b[d], ob = op_b[d];
  __syncthreads();
  if (tid < 64) {
    int lane = tid;
    float ar = (lane == 0) ? 1.f : 0.f, ai = 0.f;
#pragma unroll
    for (int i = 0; i < kNQ; ++i) fb_ry(csb[i], i, lane, ar, ai);
    fb_ansatz(csb+6, lane, ar, ai);  fb_ansatz(csb+36, lane, ar, ai);
    fb_ansatz(csb+66, lane, ar, ai); fb_ansatz(csb+96, lane, ar, ai);
#pragma unroll
    for (int i = 0; i < kNQ; ++i) {
      int m = 1 << (5-i);
      float pr = __shfl_xor(ar, m, 64), pi = __shfl_xor(ai, m, 64);
      int bit = (lane >> (5-i)) & 1;
      float nrm = fmaf(ar,ar,ai*ai);
      float abr, abi, zz;
      if (bit) { abr = 0.f; abi = 0.f; zz = -nrm; }
      else { abr = fmaf(ar,pr,ai*pi); abi = fmaf(ar,pi,-ai*pr); zz = nrm; }
#pragma unroll
      for (int o = 32; o; o >>= 1) {
        abr += __shfl_xor(abr,o,64); abi += __shfl_xor(abi,o,64); zz += __shfl_xor(zz,o,64);
      }
      if (lane == 0) { qv[i] = 2.f*abr; qv[kNQ+i] = 2.f*abi; qv[2*kNQ+i] = zz; }
    }
  }
  __syncthreads();
  {
    float acc = ob;
#pragma unroll
    for (int jj = 0; jj < 18; ++jj) acc = fmaf(qv[jj], ow[jj], acc);
    float v = acc, v2 = acc*acc;
#pragma unroll
    for (int o = 32; o; o >>= 1) { v += __shfl_xor(v,o,64); v2 += __shfl_xor(v2,o,64); }
    if ((tid & 63) == 0) { red[tid>>6] = v; red[2+(tid>>6)] = v2; }
    __syncthreads();
    float s1 = red[0]+red[1], s2 = red[2]+red[3];
    float m = s1*(1.f/kDM), var = s2*(1.f/kDM) - m*m;
    float xn = fmaf((acc-m)*rsqrtf(var+1e-5f), g2, b2);
    cf[(size_t)chunk*kDM + d] = fast_silu(xn);
  }
}

__global__ __launch_bounds__(256) void k_scl_fb(
    const float* __restrict__ cf,
    const float* __restrict__ sa1_w, const float* __restrict__ sa1_b,
    const float* __restrict__ sa2_w, const float* __restrict__ sa2_b,
    float* __restrict__ scl)
{
  int tid = threadIdx.x, wid = tid >> 6, lane = tid & 63;
  int pair = blockIdx.x * 4 + wid;
  int j = lane & 31, hh = lane >> 5;
  const float4* row = (const float4*)(cf + (size_t)pair*kDM + hh*64);
  const float* wp = sa1_w + (hh*64)*32 + j;
  float acc = 0.f;
#pragma unroll
  for (int q = 0; q < 16; ++q) {
    float4 v = row[q];
    acc = fmaf(v.x,wp[(q*4+0)*32],acc); acc = fmaf(v.y,wp[(q*4+1)*32],acc);
    acc = fmaf(v.z,wp[(q*4+2)*32],acc); acc = fmaf(v.w,wp[(q*4+3)*32],acc);
  }
  acc += __shfl_xor(acc, 32, 64);
  float hv = fast_tanh(acc + sa1_b[j]);
  float v = hv * sa2_w[j];
#pragma unroll
  for (int o = 16; o; o >>= 1) v += __shfl_xor(v, o, 64);
  if (lane == 0) scl[pair] = v + sa2_b[0];
}

// ---------------------------------------------------------------------------

extern "C" void kernel_launch(void* const* d_in, const int* in_sizes, int n_in,
                              void* d_out, int out_size, void* d_ws, size_t ws_size,
                              hipStream_t stream) {
  const float* x      = (const float*)d_in[0];
  const float* conv_w = (const float*)d_in[1];
  const float* conv_b = (const float*)d_in[2];
  const float* ln1_g  = (const float*)d_in[3];
  const float* ln1_b  = (const float*)d_in[4];
  const float* ca1_w  = (const float*)d_in[5];
  const float* ca1_b  = (const float*)d_in[6];
  const float* ca2_w  = (const float*)d_in[7];
  const float* ca2_b  = (const float*)d_in[8];
  const float* pp_w   = (const float*)d_in[9];
  const float* pp_b   = (const float*)d_in[10];
  const float* ep_w   = (const float*)d_in[11];
  const float* ep_b   = (const float*)d_in[12];
  const float* op_w   = (const float*)d_in[13];
  const float* op_b   = (const float*)d_in[14];
  const float* ln2_g  = (const float*)d_in[15];
  const float* ln2_b  = (const float*)d_in[16];
  const float* sa1_w  = (const float*)d_in[17];
  const float* sa1_b  = (const float*)d_in[18];
  const float* sa2_w  = (const float*)d_in[19];
  const float* sa2_b  = (const float*)d_in[20];
  const float* cl1_w  = (const float*)d_in[21];
  const float* cl1_b  = (const float*)d_in[22];
  const float* cl2_w  = (const float*)d_in[23];
  const float* cl2_b  = (const float*)d_in[24];
  float* out = (float*)d_out;

  const size_t nch   = (size_t)kBATCH * kNCH;  // 16384
  const size_t fCS   = nch * 256;              // cs pairs
  const size_t fA    = nch * kDM;
  // tier0: csA + separate cf + sclb (no aliasing; fused k_circ_post)
  const size_t need0 = (fCS + fA + nch) * sizeof(float);         // 25.2 MB
  // tier1: csA aliased with cf + qv + sclb (R13 path)
  const size_t need1 = (fCS + nch * 18 + nch) * sizeof(float);   // 18.0 MB
  const size_t need2 = (fA + nch * 18 + nch) * sizeof(float);    // 9.5 MB

  if (ws_size >= need0) {
    // tier0: fused tail. csA read-only for k_circ_post; cf separate.
    float* csA   = (float*)d_ws;
    float* cf2   = csA + fCS;
    float* sclb  = cf2 + fA;
    k_pre8<<<(kBATCH * kNCH) / 8, 128, 0, stream>>>(
        x, conv_w, conv_b, ln1_g, ln1_b, ca1_w, ca1_b, ca2_w, ca2_b,
        pp_w, pp_b, ep_w, ep_b, csA, 1);
    k_circ_post<<<(kBATCH * kNCH) / 16, 256, 0, stream>>>(
        csA, op_w, op_b, ln2_g, ln2_b, sa1_w, sa1_b, sa2_w, sa2_b, cf2, sclb);
    k_pool_cf<<<kBATCH, 512, 0, stream>>>(
        cf2, sclb, cl1_w, cl1_b, cl2_w, cl2_b, out);
  } else if (ws_size >= need1) {
    // tier1: R13 exact path. csA dead after k_circ_cs; cf (base) after k_post.
    float* csA   = (float*)d_ws;
    float* cf    = csA;
    float* qv_g  = csA + fCS;
    float* sclb  = qv_g + nch * 18;
    k_pre8<<<(kBATCH * kNCH) / 8, 128, 0, stream>>>(
        x, conv_w, conv_b, ln1_g, ln1_b, ca1_w, ca1_b, ca2_w, ca2_b,
        pp_w, pp_b, ep_w, ep_b, csA, 1);
    k_circ_cs<<<(kBATCH * kNCH) / 16, 64, 0, stream>>>(csA, qv_g);
    k_post<<<kBATCH * kNCH, 128, 0, stream>>>(
        qv_g, op_w, op_b, ln2_g, ln2_b, sa1_w, sa1_b, sa2_w, sa2_b, cf, sclb);
    k_pool_cf<<<kBATCH, 512, 0, stream>>>(
        cf, sclb, cl1_w, cl1_b, cl2_w, cl2_b, out);
  } else if (ws_size >= need2) {
    // tier2: half-angles; k_circ computes sincos.
    float* A     = (float*)d_ws;
    float* qv_g  = A + fA;
    float* sclb  = qv_g + nch * 18;
    k_pre8<<<(kBATCH * kNCH) / 8, 128, 0, stream>>>(
        x, conv_w, conv_b, ln1_g, ln1_b, ca1_w, ca1_b, ca2_w, ca2_b,
        pp_w, pp_b, ep_w, ep_b, A, 0);
    k_circ<<<(kBATCH * kNCH) / 16, 64, 0, stream>>>(A, qv_g);
    k_post<<<kBATCH * kNCH, 128, 0, stream>>>(
        qv_g, op_w, op_b, ln2_g, ln2_b, sa1_w, sa1_b, sa2_w, sa2_b, A, sclb);
    k_pool_cf<<<kBATCH, 512, 0, stream>>>(
        A, sclb, cl1_w, cl1_b, cl2_w, cl2_b, out);
  } else {
    // tier3: R8 fallback.
    float* cf   = (float*)d_ws;
    float* sclb = cf + nch * kDM;
    k_chunk_fb<<<kBATCH * kNCH, 128, 0, stream>>>(
        x, conv_w, conv_b, ln1_g, ln1_b, ca1_w, ca1_b, ca2_w, ca2_b,
        pp_w, pp_b, ep_w, ep_b, op_w, op_b, ln2_g, ln2_b, cf);
    k_scl_fb<<<(kBATCH * kNCH) / 4, 256, 0, stream>>>(cf, sa1_w, sa1_b, sa2_w, sa2_b, sclb);
    k_pool_cf<<<kBATCH, 512, 0, stream>>>(cf, sclb, cl1_w, cl1_b, cl2_w, cl2_b, out);
  }
}